// Round 5
// baseline (260.396 us; speedup 1.0000x reference)
//
#include <hip/hip_runtime.h>
#include <hip/hip_bf16.h>

// B=1, H=8, L=4096, D=64; 64x64 blocks; 16 samples/block. Inputs f32, output f32.
#define H_ 8
#define L_ 4096
#define D_ 64
#define NB_ 64

typedef __attribute__((ext_vector_type(8))) short bf16x8;
typedef __attribute__((ext_vector_type(4))) float f32x4;

__device__ __forceinline__ unsigned short f2bf(float x) {   // RNE f32->bf16
    unsigned u = __float_as_uint(x);
    u += 0x7fff + ((u >> 16) & 1);
    return (unsigned short)(u >> 16);
}
__device__ __forceinline__ float bf2f(unsigned short s) {
    return __uint_as_float(((unsigned)s) << 16);
}

// ---------------------------------------------------------------------------
// Kernel A (v3): block mask. One block per (h, qb) -> grid 512 (2 blocks/CU,
// 8 waves/CU; v2's grid-256 capped occupancy at 12.5% and was latency-bound).
// f32 math with __expf (v_exp rel err ~1e-6 == reorder-noise class; libm expf
// was the VGPR=256 culprit). 16 rows x 4 chunks of 256 cols, 4x4 reg tiles.
// E[row][kb] accumulated via 16-lane shfl tree + unique-writer LDS RMW.
// ---------------------------------------------------------------------------
__global__ __launch_bounds__(256) void mask_kernel3(
    const float* __restrict__ q, const float* __restrict__ k,
    const int* __restrict__ sidxq, const int* __restrict__ sidxk,
    unsigned long long* __restrict__ maskbits)
{
    const int h   = blockIdx.x >> 6;
    const int qb  = blockIdx.x & 63;
    const int tid = threadIdx.x;
    const int rg  = tid >> 6;           // wave id = rowgroup (rows rg*4..rg*4+3)
    const int cg  = tid & 63;           // lane: cols cg + 64*j (j=0..3) per chunk

    __shared__ float sq[16][68];        // 16 sampled q rows          (4.3 KB)
    __shared__ float skc[256][68];      // 256-sampled-k-col chunk    (69.6 KB)
    __shared__ float E[16][64];         // exp-mass per (row, kb)     (4 KB)
    __shared__ float Z[16];
    __shared__ float pooled[64];
    __shared__ int iq[16], ik[16];

    if (tid < 16) { iq[tid] = sidxq[h*16 + tid]; ik[tid] = sidxk[h*16 + tid]; }
    for (int e = tid; e < 16*64; e += 256) (&E[0][0])[e] = 0.f;
    __syncthreads();

    // stage 16 sampled q rows (one b128 per thread)
    {
        int j = tid >> 4, d4 = tid & 15;
        int grow = h*L_ + qb*64 + iq[j];
        *(float4*)&sq[j][d4*4] = *(const float4*)(q + (size_t)grow*D_ + d4*4);
    }

    for (int cc = 0; cc < 4; ++cc) {
        // stage chunk: 256 sampled k columns (row-gather, coalesced per row)
        for (int i = tid; i < 4096; i += 256) {
            int col = i >> 4, d4 = i & 15;
            int colg = cc*256 + col;
            int grow = h*L_ + (colg >> 4)*64 + ik[colg & 15];
            *(float4*)&skc[col][d4*4] = *(const float4*)(k + (size_t)grow*D_ + d4*4);
        }
        __syncthreads();

        float acc[4][4] = {{0.f,0.f,0.f,0.f},{0.f,0.f,0.f,0.f},
                           {0.f,0.f,0.f,0.f},{0.f,0.f,0.f,0.f}};
        #pragma unroll
        for (int d4 = 0; d4 < 16; ++d4) {
            float4 qv[4];
            #pragma unroll
            for (int i = 0; i < 4; ++i) qv[i] = *(const float4*)&sq[rg*4 + i][d4*4];  // broadcast
            #pragma unroll
            for (int j = 0; j < 4; ++j) {
                float4 kv = *(const float4*)&skc[cg + 64*j][d4*4];   // 2-way alias: free
                #pragma unroll
                for (int i = 0; i < 4; ++i)
                    acc[i][j] += qv[i].x*kv.x + qv[i].y*kv.y + qv[i].z*kv.z + qv[i].w*kv.w;
            }
        }
        // exp + accumulate E: lanes sharing (cg>>4, j) share one kb.
        #pragma unroll
        for (int j = 0; j < 4; ++j) {
            int kb = cc*16 + (cg >> 4) + 4*j;
            #pragma unroll
            for (int i = 0; i < 4; ++i) {
                float p = __expf(acc[i][j] * 0.125f);   // |s|<~6: no max-sub needed
                p += __shfl_xor(p, 1);
                p += __shfl_xor(p, 2);
                p += __shfl_xor(p, 4);
                p += __shfl_xor(p, 8);
                if ((cg & 15) == 0) E[rg*4 + i][kb] += p;   // unique (row,kb) writer
            }
        }
        __syncthreads();   // compute done before next chunk overwrites skc
    }

    if (tid < 16) {
        float s = 0.f;
        #pragma unroll
        for (int kb = 0; kb < 64; ++kb) s += E[tid][kb];
        Z[tid] = s;
    }
    __syncthreads();
    if (tid < 64) {
        float s = 0.f;
        #pragma unroll
        for (int t = 0; t < 16; ++t) s += E[t][tid] / Z[t];
        pooled[tid] = s;
    }
    __syncthreads();
    // top-p 0.5, stable descending rank (ties: lower index first)
    if (tid < 64) {
        float pi = pooled[tid];
        float tot = 0.f, bef = 0.f;
        for (int j2 = 0; j2 < 64; ++j2) {
            float pj = pooled[j2];
            tot += pj;
            if (pj > pi || (pj == pi && j2 < tid)) bef += pj;
        }
        bool att = (bef / tot) < 0.5f;
        unsigned long long bits = __ballot(att);   // wave 0
        if (tid == 0) maskbits[h*64 + qb] = bits;
    }
}

// ---------------------------------------------------------------------------
// Preprocess: per (h, tile) build bf16 ws tensors once.
//   Qhi/Qlo: row-major.  Khi: row-major, d-chunks(8 shorts) XOR-swizzled by
//   (row&7).  Vthi: transposed [d][key], key-chunks XOR-swizzled by (d&7).
// (Vtlo dropped in round 5: PV error is a softmax-weighted average of
//  independent bf16 roundings -> ~1-2e-3, within the 8.1e-3 threshold.)
// ---------------------------------------------------------------------------
__global__ __launch_bounds__(256) void prep_kernel(
    const float* __restrict__ q, const float* __restrict__ k, const float* __restrict__ v,
    unsigned short* __restrict__ qhi, unsigned short* __restrict__ qlo,
    unsigned short* __restrict__ khi,
    unsigned short* __restrict__ vth)
{
    const int h  = blockIdx.x >> 6;
    const int tb = blockIdx.x & 63;
    const int tid = threadIdx.x;
    __shared__ float vst[64][68];

    const size_t te = ((size_t)(h*64 + tb)) << 12;   // tile base (elements)
    // --- Q: straight hi/lo ---
    const float4* qg = (const float4*)(q + te);
    for (int i4 = tid; i4 < 1024; i4 += 256) {
        float4 t = qg[i4];
        ushort4 hi, lo;
        hi.x = f2bf(t.x); lo.x = f2bf(t.x - bf2f(hi.x));
        hi.y = f2bf(t.y); lo.y = f2bf(t.y - bf2f(hi.y));
        hi.z = f2bf(t.z); lo.z = f2bf(t.z - bf2f(hi.z));
        hi.w = f2bf(t.w); lo.w = f2bf(t.w - bf2f(hi.w));
        *(ushort4*)(qhi + te + i4*4) = hi;
        *(ushort4*)(qlo + te + i4*4) = lo;
    }
    // --- K: hi only, swizzled ---
    const float4* kg = (const float4*)(k + te);
    for (int i4 = tid; i4 < 1024; i4 += 256) {
        float4 t = kg[i4];
        int r = i4 >> 4, c4 = i4 & 15;
        int sch = (c4 >> 1) ^ (r & 7);
        ushort4 hi;
        hi.x = f2bf(t.x); hi.y = f2bf(t.y); hi.z = f2bf(t.z); hi.w = f2bf(t.w);
        *(ushort4*)(khi + te + r*64 + sch*8 + (c4 & 1)*4) = hi;
    }
    // --- V: transpose via LDS, hi only, swizzled ---
    const float4* vg = (const float4*)(v + te);
    for (int i4 = tid; i4 < 1024; i4 += 256) {
        float4 t = vg[i4];
        *(float4*)&vst[i4 >> 4][(i4 & 15)*4] = t;
    }
    __syncthreads();
    for (int u = tid; u < 512; u += 256) {
        int d = u >> 3, kc8 = u & 7;          // keys kc8*8..kc8*8+7
        int sch = kc8 ^ (d & 7);
        ushort4 h0, h1;
        h0.x = f2bf(vst[kc8*8+0][d]); h0.y = f2bf(vst[kc8*8+1][d]);
        h0.z = f2bf(vst[kc8*8+2][d]); h0.w = f2bf(vst[kc8*8+3][d]);
        h1.x = f2bf(vst[kc8*8+4][d]); h1.y = f2bf(vst[kc8*8+5][d]);
        h1.z = f2bf(vst[kc8*8+6][d]); h1.w = f2bf(vst[kc8*8+7][d]);
        *(ushort4*)(vth + te + d*64 + sch*8 + 0) = h0;
        *(ushort4*)(vth + te + d*64 + sch*8 + 4) = h1;
    }
}

// ---------------------------------------------------------------------------
// Kernel B (fast): block-sparse flash attention from preprocessed ws.
//   S  = (Qhi+Qlo)*Khi    PV = P*Vthi
// Register-double-buffered staging, one barrier/iter.
// ---------------------------------------------------------------------------
__global__ __launch_bounds__(256, 2) void attn_fast(
    const unsigned short* __restrict__ qhi, const unsigned short* __restrict__ qlo,
    const unsigned short* __restrict__ khi,
    const unsigned short* __restrict__ vth,
    const unsigned long long* __restrict__ maskbits,
    float* __restrict__ out)
{
    const int h    = blockIdx.x >> 6;
    const int qb   = blockIdx.x & 63;
    const int tid  = threadIdx.x;
    const int wave = tid >> 6;
    const int lane = tid & 63;
    const int l16  = lane & 15;
    const int quad = lane >> 4;

    __shared__ __align__(16) unsigned short bufK[2][4096];
    __shared__ __align__(16) unsigned short bufVh[2][4096];
    __shared__ __align__(16) unsigned short ps[4][16][80];

    // Q fragments straight from global ws (A-layout: m=l16, k=quad*8+j+32kc)
    const size_t qoff = (((size_t)(h*64 + qb)) << 12) + (size_t)(wave*16 + l16)*64;
    bf16x8 qfh[2], qfl[2];
    qfh[0] = *(const bf16x8*)(qhi + qoff + quad*8);
    qfh[1] = *(const bf16x8*)(qhi + qoff + 32 + quad*8);
    qfl[0] = *(const bf16x8*)(qlo + qoff + quad*8);
    qfl[1] = *(const bf16x8*)(qlo + qoff + 32 + quad*8);

    const unsigned long long bm = maskbits[(h << 6) + qb];

    float m_i[4], l_i[4];
    f32x4 oacc[4];
    #pragma unroll
    for (int r = 0; r < 4; ++r) { m_i[r] = -1e30f; l_i[r] = 0.f; }
    #pragma unroll
    for (int t = 0; t < 4; ++t) oacc[t] = (f32x4){0.f, 0.f, 0.f, 0.f};

    bf16x8 rK[2], rVh[2];
    auto stage_load = [&](int kb) {
        const size_t tb = ((size_t)(h*64 + kb)) << 12;
        const bf16x8* gk = (const bf16x8*)(khi + tb);
        const bf16x8* gh = (const bf16x8*)(vth + tb);
        rK[0]  = gk[tid]; rK[1]  = gk[tid + 256];
        rVh[0] = gh[tid]; rVh[1] = gh[tid + 256];
    };
    auto stage_write = [&](int b) {
        ((bf16x8*)&bufK [b][0])[tid] = rK[0];  ((bf16x8*)&bufK [b][0])[tid+256] = rK[1];
        ((bf16x8*)&bufVh[b][0])[tid] = rVh[0]; ((bf16x8*)&bufVh[b][0])[tid+256] = rVh[1];
    };

    auto compute = [&](int b) {
        // S = Q Khi^T
        f32x4 sacc[4];
        #pragma unroll
        for (int t = 0; t < 4; ++t) sacc[t] = (f32x4){0.f, 0.f, 0.f, 0.f};
        #pragma unroll
        for (int t = 0; t < 4; ++t) {
            #pragma unroll
            for (int kc = 0; kc < 2; ++kc) {
                bf16x8 kf = *(const bf16x8*)&bufK[b][(t*16 + l16)*64 + (((kc*4 + quad) ^ (l16 & 7))*8)];
                sacc[t] = __builtin_amdgcn_mfma_f32_16x16x32_bf16(qfh[kc], kf, sacc[t], 0, 0, 0);
                sacc[t] = __builtin_amdgcn_mfma_f32_16x16x32_bf16(qfl[kc], kf, sacc[t], 0, 0, 0);
            }
        }
        #pragma unroll
        for (int t = 0; t < 4; ++t) sacc[t] *= 0.125f;

        // online softmax (rows: quad*4 + r; reductions over 16-lane group)
        float rowmax[4];
        #pragma unroll
        for (int r = 0; r < 4; ++r)
            rowmax[r] = fmaxf(fmaxf(sacc[0][r], sacc[1][r]), fmaxf(sacc[2][r], sacc[3][r]));
        #pragma unroll
        for (int off = 1; off < 16; off <<= 1)
            #pragma unroll
            for (int r = 0; r < 4; ++r)
                rowmax[r] = fmaxf(rowmax[r], __shfl_xor(rowmax[r], off));

        float al[4], rs[4];
        #pragma unroll
        for (int r = 0; r < 4; ++r) {
            float mnew = fmaxf(m_i[r], rowmax[r]);
            al[r] = __expf(m_i[r] - mnew);
            m_i[r] = mnew;
            float acc = 0.f;
            #pragma unroll
            for (int t = 0; t < 4; ++t) {
                float p = __expf(sacc[t][r] - mnew);
                unsigned short pb = f2bf(p);
                ps[wave][quad*4 + r][t*16 + l16] = pb;
                acc += bf2f(pb);    // l from ROUNDED p: self-consistent normalization
            }
            rs[r] = acc;
        }
        #pragma unroll
        for (int off = 1; off < 16; off <<= 1)
            #pragma unroll
            for (int r = 0; r < 4; ++r)
                rs[r] += __shfl_xor(rs[r], off);
        #pragma unroll
        for (int r = 0; r < 4; ++r) l_i[r] = l_i[r] * al[r] + rs[r];
        #pragma unroll
        for (int t = 0; t < 4; ++t)
            #pragma unroll
            for (int r = 0; r < 4; ++r) oacc[t][r] *= al[r];

        // PV (same-wave ps write->read ordered by lgkmcnt)
        bf16x8 pf[2];
        #pragma unroll
        for (int kc = 0; kc < 2; ++kc)
            pf[kc] = *(const bf16x8*)&ps[wave][l16][kc*32 + quad*8];
        #pragma unroll
        for (int t = 0; t < 4; ++t) {
            #pragma unroll
            for (int kc = 0; kc < 2; ++kc) {
                bf16x8 vh = *(const bf16x8*)&bufVh[b][(t*16 + l16)*64 + (((kc*4 + quad) ^ (l16 & 7))*8)];
                oacc[t] = __builtin_amdgcn_mfma_f32_16x16x32_bf16(pf[kc], vh, oacc[t], 0, 0, 0);
            }
        }
    };

    // double-buffered K-loop over attended blocks
    unsigned long long rem = bm;
    int kb0 = (int)__builtin_ctzll(rem); rem &= rem - 1;
    stage_load(kb0);
    stage_write(0);
    int cur = 0;
    for (;;) {
        int nxt = -1;
        if (rem) { nxt = (int)__builtin_ctzll(rem); rem &= rem - 1; stage_load(nxt); }
        __syncthreads();     // buf[cur] writes (prev iter / prologue) visible
        compute(cur);
        if (nxt < 0) break;
        stage_write(cur ^ 1);
        cur ^= 1;
    }

    // epilogue
    float* og = out + ((size_t)h*L_ + (size_t)qb*64)*D_ + (size_t)(wave*16 + quad*4)*D_;
    #pragma unroll
    for (int r = 0; r < 4; ++r) {
        float inv = 1.f / l_i[r];
        #pragma unroll
        for (int t = 0; t < 4; ++t)
            og[(size_t)r*D_ + t*16 + l16] = oacc[t][r] * inv;
    }
}

// ---------------------------------------------------------------------------
// Fallback attention (round-3, proven full-precision): only if ws too small.
// ---------------------------------------------------------------------------
__global__ __launch_bounds__(256, 3) void attn_v3(
    const float* __restrict__ q, const float* __restrict__ k, const float* __restrict__ v,
    const unsigned long long* __restrict__ maskbits, float* __restrict__ out)
{
    const int h = blockIdx.x >> 6, qb = blockIdx.x & 63;
    const int tid = threadIdx.x, wave = tid >> 6, lane = tid & 63;
    const int l16 = lane & 15, quad = lane >> 4;
    __shared__ __align__(16) unsigned short ks_hi[64][72];
    __shared__ __align__(16) unsigned short ks_lo[64][72];
    __shared__ __align__(16) unsigned short vt_hi[64][72];
    __shared__ __align__(16) unsigned short vt_lo[64][72];
    __shared__ __align__(16) unsigned short ps[4][16][72];

    const float4* qg = (const float4*)(q + ((size_t)h*L_ + (size_t)qb*64)*D_);
    for (int i4 = tid; i4 < 1024; i4 += 256) {
        float4 t = qg[i4];
        int r = i4 >> 4, c = (i4 & 15) << 2;
        ushort4 hi, lo;
        hi.x = f2bf(t.x); lo.x = f2bf(t.x - bf2f(hi.x));
        hi.y = f2bf(t.y); lo.y = f2bf(t.y - bf2f(hi.y));
        hi.z = f2bf(t.z); lo.z = f2bf(t.z - bf2f(hi.z));
        hi.w = f2bf(t.w); lo.w = f2bf(t.w - bf2f(hi.w));
        *(ushort4*)&ks_hi[r][c] = hi;
        *(ushort4*)&ks_lo[r][c] = lo;
    }
    const unsigned long long bm = maskbits[(h << 6) + qb];
    __syncthreads();
    bf16x8 qhi2[2], qlo2[2];
    #pragma unroll
    for (int kc = 0; kc < 2; ++kc) {
        qhi2[kc] = *(const bf16x8*)&ks_hi[wave*16 + l16][kc*32 + quad*8];
        qlo2[kc] = *(const bf16x8*)&ks_lo[wave*16 + l16][kc*32 + quad*8];
    }
    __syncthreads();
    float m_i[4], l_i[4];
    f32x4 oacc[4];
    #pragma unroll
    for (int r = 0; r < 4; ++r) { m_i[r] = -1e30f; l_i[r] = 0.f; }
    #pragma unroll
    for (int t = 0; t < 4; ++t) oacc[t] = (f32x4){0.f, 0.f, 0.f, 0.f};
    for (int kb = 0; kb < 64; ++kb) {
        if (!((bm >> kb) & 1ull)) continue;
        const float4* kg = (const float4*)(k + ((size_t)h*L_ + (size_t)kb*64)*D_);
        const float*  vg = v + ((size_t)h*L_ + (size_t)kb*64)*D_;
        for (int i4 = tid; i4 < 1024; i4 += 256) {
            float4 t = kg[i4];
            int r = i4 >> 4, c = (i4 & 15) << 2;
            ushort4 hi, lo;
            hi.x = f2bf(t.x); lo.x = f2bf(t.x - bf2f(hi.x));
            hi.y = f2bf(t.y); lo.y = f2bf(t.y - bf2f(hi.y));
            hi.z = f2bf(t.z); lo.z = f2bf(t.z - bf2f(hi.z));
            hi.w = f2bf(t.w); lo.w = f2bf(t.w - bf2f(hi.w));
            *(ushort4*)&ks_hi[r][c] = hi;
            *(ushort4*)&ks_lo[r][c] = lo;
        }
        for (int tsk = tid; tsk < 512; tsk += 256) {
            int rp = tsk >> 4;
            int c  = (tsk & 15) << 2;
            float4 a0 = *(const float4*)(vg + (size_t)(2*rp)*D_ + c);
            float4 a1 = *(const float4*)(vg + (size_t)(2*rp+1)*D_ + c);
            #pragma unroll
            for (int j = 0; j < 4; ++j) {
                float x0 = (j==0)?a0.x:(j==1)?a0.y:(j==2)?a0.z:a0.w;
                float x1 = (j==0)?a1.x:(j==1)?a1.y:(j==2)?a1.z:a1.w;
                unsigned short h0 = f2bf(x0), h1b = f2bf(x1);
                *(unsigned*)&vt_hi[c+j][2*rp] = (unsigned)h0 | ((unsigned)h1b << 16);
                unsigned short lo0 = f2bf(x0 - bf2f(h0)), lo1 = f2bf(x1 - bf2f(h1b));
                *(unsigned*)&vt_lo[c+j][2*rp] = (unsigned)lo0 | ((unsigned)lo1 << 16);
            }
        }
        __syncthreads();
        f32x4 sacc[4];
        #pragma unroll
        for (int t = 0; t < 4; ++t) sacc[t] = (f32x4){0.f, 0.f, 0.f, 0.f};
        #pragma unroll
        for (int t = 0; t < 4; ++t) {
            #pragma unroll
            for (int kc = 0; kc < 2; ++kc) {
                bf16x8 khi2 = *(const bf16x8*)&ks_hi[t*16 + l16][kc*32 + quad*8];
                bf16x8 klo2 = *(const bf16x8*)&ks_lo[t*16 + l16][kc*32 + quad*8];
                sacc[t] = __builtin_amdgcn_mfma_f32_16x16x32_bf16(qhi2[kc], khi2, sacc[t], 0, 0, 0);
                sacc[t] = __builtin_amdgcn_mfma_f32_16x16x32_bf16(qhi2[kc], klo2, sacc[t], 0, 0, 0);
                sacc[t] = __builtin_amdgcn_mfma_f32_16x16x32_bf16(qlo2[kc], khi2, sacc[t], 0, 0, 0);
            }
        }
        #pragma unroll
        for (int t = 0; t < 4; ++t) sacc[t] *= 0.125f;
        float rowmax[4];
        #pragma unroll
        for (int r = 0; r < 4; ++r)
            rowmax[r] = fmaxf(fmaxf(sacc[0][r], sacc[1][r]), fmaxf(sacc[2][r], sacc[3][r]));
        #pragma unroll
        for (int off = 1; off < 16; off <<= 1)
            #pragma unroll
            for (int r = 0; r < 4; ++r)
                rowmax[r] = fmaxf(rowmax[r], __shfl_xor(rowmax[r], off));
        float al[4], rs[4];
        #pragma unroll
        for (int r = 0; r < 4; ++r) {
            float mnew = fmaxf(m_i[r], rowmax[r]);
            al[r] = __expf(m_i[r] - mnew);
            m_i[r] = mnew;
            float acc = 0.f;
            #pragma unroll
            for (int t = 0; t < 4; ++t) {
                float p = __expf(sacc[t][r] - mnew);
                unsigned short pb = f2bf(p);
                ps[wave][quad*4 + r][t*16 + l16] = pb;
                acc += bf2f(pb);
            }
            rs[r] = acc;
        }
        #pragma unroll
        for (int off = 1; off < 16; off <<= 1)
            #pragma unroll
            for (int r = 0; r < 4; ++r)
                rs[r] += __shfl_xor(rs[r], off);
        #pragma unroll
        for (int r = 0; r < 4; ++r) l_i[r] = l_i[r] * al[r] + rs[r];
        #pragma unroll
        for (int t = 0; t < 4; ++t)
            #pragma unroll
            for (int r = 0; r < 4; ++r) oacc[t][r] *= al[r];
        bf16x8 pf[2];
        #pragma unroll
        for (int kc = 0; kc < 2; ++kc)
            pf[kc] = *(const bf16x8*)&ps[wave][l16][kc*32 + quad*8];
        #pragma unroll
        for (int t = 0; t < 4; ++t) {
            #pragma unroll
            for (int kc = 0; kc < 2; ++kc) {
                bf16x8 vhif = *(const bf16x8*)&vt_hi[t*16 + l16][kc*32 + quad*8];
                bf16x8 vlof = *(const bf16x8*)&vt_lo[t*16 + l16][kc*32 + quad*8];
                oacc[t] = __builtin_amdgcn_mfma_f32_16x16x32_bf16(pf[kc], vhif, oacc[t], 0, 0, 0);
                oacc[t] = __builtin_amdgcn_mfma_f32_16x16x32_bf16(pf[kc], vlof, oacc[t], 0, 0, 0);
            }
        }
        __syncthreads();
    }
    float* og = out + ((size_t)h*L_ + (size_t)qb*64)*D_ + (size_t)(wave*16 + quad*4)*D_;
    #pragma unroll
    for (int r = 0; r < 4; ++r) {
        float inv = 1.f / l_i[r];
        #pragma unroll
        for (int t = 0; t < 4; ++t)
            og[(size_t)r*D_ + t*16 + l16] = oacc[t][r] * inv;
    }
}

extern "C" void kernel_launch(void* const* d_in, const int* in_sizes, int n_in,
                              void* d_out, int out_size, void* d_ws, size_t ws_size,
                              hipStream_t stream) {
    const float* q = (const float*)d_in[0];
    const float* k = (const float*)d_in[1];
    const float* v = (const float*)d_in[2];
    const int* siq = (const int*)d_in[3];
    const int* sik = (const int*)d_in[4];
    float* out = (float*)d_out;

    char* ws = (char*)d_ws;
    unsigned long long* mask = (unsigned long long*)ws;          // 4 KB
    const size_t TEN = (size_t)H_*L_*D_;                         // 2,097,152 elems
    unsigned short* qhi = (unsigned short*)(ws + 4096);
    unsigned short* qlo = qhi + TEN;
    unsigned short* khi = qlo + TEN;
    unsigned short* vth = khi + TEN;
    const size_t need = 4096 + 4*TEN*sizeof(unsigned short);     // ~16.8 MB

    mask_kernel3<<<dim3(H_*NB_), dim3(256), 0, stream>>>(q, k, siq, sik, mask);
    if (ws_size >= need) {
        prep_kernel<<<dim3(H_*NB_), dim3(256), 0, stream>>>(q, k, v, qhi, qlo, khi, vth);
        attn_fast<<<dim3(H_*NB_), dim3(256), 0, stream>>>(qhi, qlo, khi, vth, mask, out);
    } else {
        attn_v3<<<dim3(H_*NB_), dim3(256), 0, stream>>>(q, k, v, mask, out);
    }
}

// Round 6
// 198.730 us; speedup vs baseline: 1.3103x; 1.3103x over previous
//
#include <hip/hip_runtime.h>
#include <hip/hip_bf16.h>

// B=1, H=8, L=4096, D=64; 64x64 blocks; 16 samples/block. Inputs f32, output f32.
#define H_ 8
#define L_ 4096
#define D_ 64
#define NB_ 64

typedef __attribute__((ext_vector_type(8))) short bf16x8;
typedef __attribute__((ext_vector_type(4))) float f32x4;

__device__ __forceinline__ unsigned short f2bf(float x) {   // RNE f32->bf16
    unsigned u = __float_as_uint(x);
    u += 0x7fff + ((u >> 16) & 1);
    return (unsigned short)(u >> 16);
}
__device__ __forceinline__ float bf2f(unsigned short s) {
    return __uint_as_float(((unsigned)s) << 16);
}

// ---------------------------------------------------------------------------
// Kernel A (v4): block mask. One block per (h, qb), grid 512.
// v3 post-mortem: VGPR=256 + WRITE_SIZE=5.1MB on a 4KB-output kernel =
// SCRATCH SPILLS (not expf). Fix: __launch_bounds__(256,4) caps VGPR at 128;
// 2x4 thread tiles (8 accs) + unroll-4 d-loop bound live ranges; chunk=128
// cols keeps LDS at 43.5 KB. Math bit-identical to v3 (each kb's 16 cols
// inside one chunk; same shfl tree & accumulation order) -> same mask bits.
// ---------------------------------------------------------------------------
__global__ __launch_bounds__(256, 4) void mask_kernel4(
    const float* __restrict__ q, const float* __restrict__ k,
    const int* __restrict__ sidxq, const int* __restrict__ sidxk,
    unsigned long long* __restrict__ maskbits)
{
    const int h   = blockIdx.x >> 6;
    const int qb  = blockIdx.x & 63;
    const int tid = threadIdx.x;
    const int rg  = tid >> 5;           // 0..7: rows rg*2, rg*2+1
    const int cg  = tid & 31;           // cols cg + 32*j (j=0..3)

    __shared__ float sq[16][68];        // 16 sampled q rows        (4.35 KB)
    __shared__ float skc[128][68];      // 128-sampled-col k chunk  (34.8 KB)
    __shared__ float E[16][64];         // exp-mass per (row, kb)   (4 KB)
    __shared__ float Z[16];
    __shared__ float pooled[64];
    __shared__ int iq[16], ik[16];

    if (tid < 16) { iq[tid] = sidxq[h*16 + tid]; ik[tid] = sidxk[h*16 + tid]; }
    for (int e = tid; e < 16*64; e += 256) (&E[0][0])[e] = 0.f;
    __syncthreads();

    // stage 16 sampled q rows (one b128 per thread)
    {
        int j = tid >> 4, d4 = tid & 15;
        int grow = h*L_ + qb*64 + iq[j];
        *(float4*)&sq[j][d4*4] = *(const float4*)(q + (size_t)grow*D_ + d4*4);
    }

    for (int cc = 0; cc < 8; ++cc) {
        // stage chunk: 128 sampled k columns (16 lanes per row, coalesced)
        for (int i = tid; i < 2048; i += 256) {
            int col = i >> 4, d4 = i & 15;
            int colg = cc*128 + col;
            int grow = h*L_ + (colg >> 4)*64 + ik[colg & 15];
            *(float4*)&skc[col][d4*4] = *(const float4*)(k + (size_t)grow*D_ + d4*4);
        }
        __syncthreads();   // (cc=0: also covers sq/E/iq-ik staging)

        float acc[2][4] = {{0.f,0.f,0.f,0.f},{0.f,0.f,0.f,0.f}};
        #pragma unroll 4
        for (int d4 = 0; d4 < 16; ++d4) {
            float4 qv0 = *(const float4*)&sq[rg*2 + 0][d4*4];   // broadcast
            float4 qv1 = *(const float4*)&sq[rg*2 + 1][d4*4];
            #pragma unroll
            for (int j = 0; j < 4; ++j) {
                float4 kv = *(const float4*)&skc[cg + 32*j][d4*4];
                acc[0][j] += qv0.x*kv.x + qv0.y*kv.y + qv0.z*kv.z + qv0.w*kv.w;
                acc[1][j] += qv1.x*kv.x + qv1.y*kv.y + qv1.z*kv.z + qv1.w*kv.w;
            }
        }
        // exp + accumulate E: 16 lanes sharing (cg>>4, j) share one kb.
        #pragma unroll
        for (int j = 0; j < 4; ++j) {
            int kb = cc*8 + (cg >> 4) + 2*j;
            #pragma unroll
            for (int i = 0; i < 2; ++i) {
                float p = __expf(acc[i][j] * 0.125f);   // |s|<~6: safe, no max-sub
                p += __shfl_xor(p, 1);
                p += __shfl_xor(p, 2);
                p += __shfl_xor(p, 4);
                p += __shfl_xor(p, 8);
                if ((cg & 15) == 0) E[rg*2 + i][kb] += p;   // unique (row,kb) writer
            }
        }
        __syncthreads();   // compute done before next chunk overwrites skc
    }

    if (tid < 16) {
        float s = 0.f;
        #pragma unroll
        for (int kb = 0; kb < 64; ++kb) s += E[tid][kb];
        Z[tid] = s;
    }
    __syncthreads();
    if (tid < 64) {
        float s = 0.f;
        #pragma unroll
        for (int t = 0; t < 16; ++t) s += E[t][tid] / Z[t];
        pooled[tid] = s;
    }
    __syncthreads();
    // top-p 0.5, stable descending rank (ties: lower index first)
    if (tid < 64) {
        float pi = pooled[tid];
        float tot = 0.f, bef = 0.f;
        for (int j2 = 0; j2 < 64; ++j2) {
            float pj = pooled[j2];
            tot += pj;
            if (pj > pi || (pj == pi && j2 < tid)) bef += pj;
        }
        bool att = (bef / tot) < 0.5f;
        unsigned long long bits = __ballot(att);   // wave 0
        if (tid == 0) maskbits[h*64 + qb] = bits;
    }
}

// ---------------------------------------------------------------------------
// Preprocess (unchanged from round 5): per (h, tile) build bf16 ws once.
//   Qhi/Qlo row-major; Khi row-major d-chunk XOR-swizzled by (row&7);
//   Vthi transposed [d][key], key-chunk XOR-swizzled by (d&7).
// ---------------------------------------------------------------------------
__global__ __launch_bounds__(256) void prep_kernel(
    const float* __restrict__ q, const float* __restrict__ k, const float* __restrict__ v,
    unsigned short* __restrict__ qhi, unsigned short* __restrict__ qlo,
    unsigned short* __restrict__ khi,
    unsigned short* __restrict__ vth)
{
    const int h  = blockIdx.x >> 6;
    const int tb = blockIdx.x & 63;
    const int tid = threadIdx.x;
    __shared__ float vst[64][68];

    const size_t te = ((size_t)(h*64 + tb)) << 12;   // tile base (elements)
    const float4* qg = (const float4*)(q + te);
    for (int i4 = tid; i4 < 1024; i4 += 256) {
        float4 t = qg[i4];
        ushort4 hi, lo;
        hi.x = f2bf(t.x); lo.x = f2bf(t.x - bf2f(hi.x));
        hi.y = f2bf(t.y); lo.y = f2bf(t.y - bf2f(hi.y));
        hi.z = f2bf(t.z); lo.z = f2bf(t.z - bf2f(hi.z));
        hi.w = f2bf(t.w); lo.w = f2bf(t.w - bf2f(hi.w));
        *(ushort4*)(qhi + te + i4*4) = hi;
        *(ushort4*)(qlo + te + i4*4) = lo;
    }
    const float4* kg = (const float4*)(k + te);
    for (int i4 = tid; i4 < 1024; i4 += 256) {
        float4 t = kg[i4];
        int r = i4 >> 4, c4 = i4 & 15;
        int sch = (c4 >> 1) ^ (r & 7);
        ushort4 hi;
        hi.x = f2bf(t.x); hi.y = f2bf(t.y); hi.z = f2bf(t.z); hi.w = f2bf(t.w);
        *(ushort4*)(khi + te + r*64 + sch*8 + (c4 & 1)*4) = hi;
    }
    const float4* vg = (const float4*)(v + te);
    for (int i4 = tid; i4 < 1024; i4 += 256) {
        float4 t = vg[i4];
        *(float4*)&vst[i4 >> 4][(i4 & 15)*4] = t;
    }
    __syncthreads();
    for (int u = tid; u < 512; u += 256) {
        int d = u >> 3, kc8 = u & 7;
        int sch = kc8 ^ (d & 7);
        ushort4 h0, h1;
        h0.x = f2bf(vst[kc8*8+0][d]); h0.y = f2bf(vst[kc8*8+1][d]);
        h0.z = f2bf(vst[kc8*8+2][d]); h0.w = f2bf(vst[kc8*8+3][d]);
        h1.x = f2bf(vst[kc8*8+4][d]); h1.y = f2bf(vst[kc8*8+5][d]);
        h1.z = f2bf(vst[kc8*8+6][d]); h1.w = f2bf(vst[kc8*8+7][d]);
        *(ushort4*)(vth + te + d*64 + sch*8 + 0) = h0;
        *(ushort4*)(vth + te + d*64 + sch*8 + 4) = h1;
    }
}

// ---------------------------------------------------------------------------
// Kernel B (unchanged from round 5): block-sparse flash attention from ws.
//   S = (Qhi+Qlo)*Khi    PV = P*Vthi
// ---------------------------------------------------------------------------
__global__ __launch_bounds__(256, 2) void attn_fast(
    const unsigned short* __restrict__ qhi, const unsigned short* __restrict__ qlo,
    const unsigned short* __restrict__ khi,
    const unsigned short* __restrict__ vth,
    const unsigned long long* __restrict__ maskbits,
    float* __restrict__ out)
{
    const int h    = blockIdx.x >> 6;
    const int qb   = blockIdx.x & 63;
    const int tid  = threadIdx.x;
    const int wave = tid >> 6;
    const int lane = tid & 63;
    const int l16  = lane & 15;
    const int quad = lane >> 4;

    __shared__ __align__(16) unsigned short bufK[2][4096];
    __shared__ __align__(16) unsigned short bufVh[2][4096];
    __shared__ __align__(16) unsigned short ps[4][16][80];

    const size_t qoff = (((size_t)(h*64 + qb)) << 12) + (size_t)(wave*16 + l16)*64;
    bf16x8 qfh[2], qfl[2];
    qfh[0] = *(const bf16x8*)(qhi + qoff + quad*8);
    qfh[1] = *(const bf16x8*)(qhi + qoff + 32 + quad*8);
    qfl[0] = *(const bf16x8*)(qlo + qoff + quad*8);
    qfl[1] = *(const bf16x8*)(qlo + qoff + 32 + quad*8);

    const unsigned long long bm = maskbits[(h << 6) + qb];

    float m_i[4], l_i[4];
    f32x4 oacc[4];
    #pragma unroll
    for (int r = 0; r < 4; ++r) { m_i[r] = -1e30f; l_i[r] = 0.f; }
    #pragma unroll
    for (int t = 0; t < 4; ++t) oacc[t] = (f32x4){0.f, 0.f, 0.f, 0.f};

    bf16x8 rK[2], rVh[2];
    auto stage_load = [&](int kb) {
        const size_t tb = ((size_t)(h*64 + kb)) << 12;
        const bf16x8* gk = (const bf16x8*)(khi + tb);
        const bf16x8* gh = (const bf16x8*)(vth + tb);
        rK[0]  = gk[tid]; rK[1]  = gk[tid + 256];
        rVh[0] = gh[tid]; rVh[1] = gh[tid + 256];
    };
    auto stage_write = [&](int b) {
        ((bf16x8*)&bufK [b][0])[tid] = rK[0];  ((bf16x8*)&bufK [b][0])[tid+256] = rK[1];
        ((bf16x8*)&bufVh[b][0])[tid] = rVh[0]; ((bf16x8*)&bufVh[b][0])[tid+256] = rVh[1];
    };

    auto compute = [&](int b) {
        f32x4 sacc[4];
        #pragma unroll
        for (int t = 0; t < 4; ++t) sacc[t] = (f32x4){0.f, 0.f, 0.f, 0.f};
        #pragma unroll
        for (int t = 0; t < 4; ++t) {
            #pragma unroll
            for (int kc = 0; kc < 2; ++kc) {
                bf16x8 kf = *(const bf16x8*)&bufK[b][(t*16 + l16)*64 + (((kc*4 + quad) ^ (l16 & 7))*8)];
                sacc[t] = __builtin_amdgcn_mfma_f32_16x16x32_bf16(qfh[kc], kf, sacc[t], 0, 0, 0);
                sacc[t] = __builtin_amdgcn_mfma_f32_16x16x32_bf16(qfl[kc], kf, sacc[t], 0, 0, 0);
            }
        }
        #pragma unroll
        for (int t = 0; t < 4; ++t) sacc[t] *= 0.125f;

        float rowmax[4];
        #pragma unroll
        for (int r = 0; r < 4; ++r)
            rowmax[r] = fmaxf(fmaxf(sacc[0][r], sacc[1][r]), fmaxf(sacc[2][r], sacc[3][r]));
        #pragma unroll
        for (int off = 1; off < 16; off <<= 1)
            #pragma unroll
            for (int r = 0; r < 4; ++r)
                rowmax[r] = fmaxf(rowmax[r], __shfl_xor(rowmax[r], off));

        float al[4], rs[4];
        #pragma unroll
        for (int r = 0; r < 4; ++r) {
            float mnew = fmaxf(m_i[r], rowmax[r]);
            al[r] = __expf(m_i[r] - mnew);
            m_i[r] = mnew;
            float acc = 0.f;
            #pragma unroll
            for (int t = 0; t < 4; ++t) {
                float p = __expf(sacc[t][r] - mnew);
                unsigned short pb = f2bf(p);
                ps[wave][quad*4 + r][t*16 + l16] = pb;
                acc += bf2f(pb);
            }
            rs[r] = acc;
        }
        #pragma unroll
        for (int off = 1; off < 16; off <<= 1)
            #pragma unroll
            for (int r = 0; r < 4; ++r)
                rs[r] += __shfl_xor(rs[r], off);
        #pragma unroll
        for (int r = 0; r < 4; ++r) l_i[r] = l_i[r] * al[r] + rs[r];
        #pragma unroll
        for (int t = 0; t < 4; ++t)
            #pragma unroll
            for (int r = 0; r < 4; ++r) oacc[t][r] *= al[r];

        bf16x8 pf[2];
        #pragma unroll
        for (int kc = 0; kc < 2; ++kc)
            pf[kc] = *(const bf16x8*)&ps[wave][l16][kc*32 + quad*8];
        #pragma unroll
        for (int t = 0; t < 4; ++t) {
            #pragma unroll
            for (int kc = 0; kc < 2; ++kc) {
                bf16x8 vh = *(const bf16x8*)&bufVh[b][(t*16 + l16)*64 + (((kc*4 + quad) ^ (l16 & 7))*8)];
                oacc[t] = __builtin_amdgcn_mfma_f32_16x16x32_bf16(pf[kc], vh, oacc[t], 0, 0, 0);
            }
        }
    };

    unsigned long long rem = bm;
    int kb0 = (int)__builtin_ctzll(rem); rem &= rem - 1;
    stage_load(kb0);
    stage_write(0);
    int cur = 0;
    for (;;) {
        int nxt = -1;
        if (rem) { nxt = (int)__builtin_ctzll(rem); rem &= rem - 1; stage_load(nxt); }
        __syncthreads();
        compute(cur);
        if (nxt < 0) break;
        stage_write(cur ^ 1);
        cur ^= 1;
    }

    float* og = out + ((size_t)h*L_ + (size_t)qb*64)*D_ + (size_t)(wave*16 + quad*4)*D_;
    #pragma unroll
    for (int r = 0; r < 4; ++r) {
        float inv = 1.f / l_i[r];
        #pragma unroll
        for (int t = 0; t < 4; ++t)
            og[(size_t)r*D_ + t*16 + l16] = oacc[t][r] * inv;
    }
}

// ---------------------------------------------------------------------------
// Fallback attention (round-3, proven full-precision): only if ws too small.
// ---------------------------------------------------------------------------
__global__ __launch_bounds__(256, 3) void attn_v3(
    const float* __restrict__ q, const float* __restrict__ k, const float* __restrict__ v,
    const unsigned long long* __restrict__ maskbits, float* __restrict__ out)
{
    const int h = blockIdx.x >> 6, qb = blockIdx.x & 63;
    const int tid = threadIdx.x, wave = tid >> 6, lane = tid & 63;
    const int l16 = lane & 15, quad = lane >> 4;
    __shared__ __align__(16) unsigned short ks_hi[64][72];
    __shared__ __align__(16) unsigned short ks_lo[64][72];
    __shared__ __align__(16) unsigned short vt_hi[64][72];
    __shared__ __align__(16) unsigned short vt_lo[64][72];
    __shared__ __align__(16) unsigned short ps[4][16][72];

    const float4* qg = (const float4*)(q + ((size_t)h*L_ + (size_t)qb*64)*D_);
    for (int i4 = tid; i4 < 1024; i4 += 256) {
        float4 t = qg[i4];
        int r = i4 >> 4, c = (i4 & 15) << 2;
        ushort4 hi, lo;
        hi.x = f2bf(t.x); lo.x = f2bf(t.x - bf2f(hi.x));
        hi.y = f2bf(t.y); lo.y = f2bf(t.y - bf2f(hi.y));
        hi.z = f2bf(t.z); lo.z = f2bf(t.z - bf2f(hi.z));
        hi.w = f2bf(t.w); lo.w = f2bf(t.w - bf2f(hi.w));
        *(ushort4*)&ks_hi[r][c] = hi;
        *(ushort4*)&ks_lo[r][c] = lo;
    }
    const unsigned long long bm = maskbits[(h << 6) + qb];
    __syncthreads();
    bf16x8 qhi2[2], qlo2[2];
    #pragma unroll
    for (int kc = 0; kc < 2; ++kc) {
        qhi2[kc] = *(const bf16x8*)&ks_hi[wave*16 + l16][kc*32 + quad*8];
        qlo2[kc] = *(const bf16x8*)&ks_lo[wave*16 + l16][kc*32 + quad*8];
    }
    __syncthreads();
    float m_i[4], l_i[4];
    f32x4 oacc[4];
    #pragma unroll
    for (int r = 0; r < 4; ++r) { m_i[r] = -1e30f; l_i[r] = 0.f; }
    #pragma unroll
    for (int t = 0; t < 4; ++t) oacc[t] = (f32x4){0.f, 0.f, 0.f, 0.f};
    for (int kb = 0; kb < 64; ++kb) {
        if (!((bm >> kb) & 1ull)) continue;
        const float4* kg = (const float4*)(k + ((size_t)h*L_ + (size_t)kb*64)*D_);
        const float*  vg = v + ((size_t)h*L_ + (size_t)kb*64)*D_;
        for (int i4 = tid; i4 < 1024; i4 += 256) {
            float4 t = kg[i4];
            int r = i4 >> 4, c = (i4 & 15) << 2;
            ushort4 hi, lo;
            hi.x = f2bf(t.x); lo.x = f2bf(t.x - bf2f(hi.x));
            hi.y = f2bf(t.y); lo.y = f2bf(t.y - bf2f(hi.y));
            hi.z = f2bf(t.z); lo.z = f2bf(t.z - bf2f(hi.z));
            hi.w = f2bf(t.w); lo.w = f2bf(t.w - bf2f(hi.w));
            *(ushort4*)&ks_hi[r][c] = hi;
            *(ushort4*)&ks_lo[r][c] = lo;
        }
        for (int tsk = tid; tsk < 512; tsk += 256) {
            int rp = tsk >> 4;
            int c  = (tsk & 15) << 2;
            float4 a0 = *(const float4*)(vg + (size_t)(2*rp)*D_ + c);
            float4 a1 = *(const float4*)(vg + (size_t)(2*rp+1)*D_ + c);
            #pragma unroll
            for (int j = 0; j < 4; ++j) {
                float x0 = (j==0)?a0.x:(j==1)?a0.y:(j==2)?a0.z:a0.w;
                float x1 = (j==0)?a1.x:(j==1)?a1.y:(j==2)?a1.z:a1.w;
                unsigned short h0 = f2bf(x0), h1b = f2bf(x1);
                *(unsigned*)&vt_hi[c+j][2*rp] = (unsigned)h0 | ((unsigned)h1b << 16);
                unsigned short lo0 = f2bf(x0 - bf2f(h0)), lo1 = f2bf(x1 - bf2f(h1b));
                *(unsigned*)&vt_lo[c+j][2*rp] = (unsigned)lo0 | ((unsigned)lo1 << 16);
            }
        }
        __syncthreads();
        f32x4 sacc[4];
        #pragma unroll
        for (int t = 0; t < 4; ++t) sacc[t] = (f32x4){0.f, 0.f, 0.f, 0.f};
        #pragma unroll
        for (int t = 0; t < 4; ++t) {
            #pragma unroll
            for (int kc = 0; kc < 2; ++kc) {
                bf16x8 khi2 = *(const bf16x8*)&ks_hi[t*16 + l16][kc*32 + quad*8];
                bf16x8 klo2 = *(const bf16x8*)&ks_lo[t*16 + l16][kc*32 + quad*8];
                sacc[t] = __builtin_amdgcn_mfma_f32_16x16x32_bf16(qhi2[kc], khi2, sacc[t], 0, 0, 0);
                sacc[t] = __builtin_amdgcn_mfma_f32_16x16x32_bf16(qhi2[kc], klo2, sacc[t], 0, 0, 0);
                sacc[t] = __builtin_amdgcn_mfma_f32_16x16x32_bf16(qlo2[kc], khi2, sacc[t], 0, 0, 0);
            }
        }
        #pragma unroll
        for (int t = 0; t < 4; ++t) sacc[t] *= 0.125f;
        float rowmax[4];
        #pragma unroll
        for (int r = 0; r < 4; ++r)
            rowmax[r] = fmaxf(fmaxf(sacc[0][r], sacc[1][r]), fmaxf(sacc[2][r], sacc[3][r]));
        #pragma unroll
        for (int off = 1; off < 16; off <<= 1)
            #pragma unroll
            for (int r = 0; r < 4; ++r)
                rowmax[r] = fmaxf(rowmax[r], __shfl_xor(rowmax[r], off));
        float al[4], rs[4];
        #pragma unroll
        for (int r = 0; r < 4; ++r) {
            float mnew = fmaxf(m_i[r], rowmax[r]);
            al[r] = __expf(m_i[r] - mnew);
            m_i[r] = mnew;
            float acc = 0.f;
            #pragma unroll
            for (int t = 0; t < 4; ++t) {
                float p = __expf(sacc[t][r] - mnew);
                unsigned short pb = f2bf(p);
                ps[wave][quad*4 + r][t*16 + l16] = pb;
                acc += bf2f(pb);
            }
            rs[r] = acc;
        }
        #pragma unroll
        for (int off = 1; off < 16; off <<= 1)
            #pragma unroll
            for (int r = 0; r < 4; ++r)
                rs[r] += __shfl_xor(rs[r], off);
        #pragma unroll
        for (int r = 0; r < 4; ++r) l_i[r] = l_i[r] * al[r] + rs[r];
        #pragma unroll
        for (int t = 0; t < 4; ++t)
            #pragma unroll
            for (int r = 0; r < 4; ++r) oacc[t][r] *= al[r];
        bf16x8 pf[2];
        #pragma unroll
        for (int kc = 0; kc < 2; ++kc)
            pf[kc] = *(const bf16x8*)&ps[wave][l16][kc*32 + quad*8];
        #pragma unroll
        for (int t = 0; t < 4; ++t) {
            #pragma unroll
            for (int kc = 0; kc < 2; ++kc) {
                bf16x8 vhif = *(const bf16x8*)&vt_hi[t*16 + l16][kc*32 + quad*8];
                bf16x8 vlof = *(const bf16x8*)&vt_lo[t*16 + l16][kc*32 + quad*8];
                oacc[t] = __builtin_amdgcn_mfma_f32_16x16x32_bf16(pf[kc], vhif, oacc[t], 0, 0, 0);
                oacc[t] = __builtin_amdgcn_mfma_f32_16x16x32_bf16(pf[kc], vlof, oacc[t], 0, 0, 0);
            }
        }
        __syncthreads();
    }
    float* og = out + ((size_t)h*L_ + (size_t)qb*64)*D_ + (size_t)(wave*16 + quad*4)*D_;
    #pragma unroll
    for (int r = 0; r < 4; ++r) {
        float inv = 1.f / l_i[r];
        #pragma unroll
        for (int t = 0; t < 4; ++t)
            og[(size_t)r*D_ + t*16 + l16] = oacc[t][r] * inv;
    }
}

extern "C" void kernel_launch(void* const* d_in, const int* in_sizes, int n_in,
                              void* d_out, int out_size, void* d_ws, size_t ws_size,
                              hipStream_t stream) {
    const float* q = (const float*)d_in[0];
    const float* k = (const float*)d_in[1];
    const float* v = (const float*)d_in[2];
    const int* siq = (const int*)d_in[3];
    const int* sik = (const int*)d_in[4];
    float* out = (float*)d_out;

    char* ws = (char*)d_ws;
    unsigned long long* mask = (unsigned long long*)ws;          // 4 KB
    const size_t TEN = (size_t)H_*L_*D_;                         // 2,097,152 elems
    unsigned short* qhi = (unsigned short*)(ws + 4096);
    unsigned short* qlo = qhi + TEN;
    unsigned short* khi = qlo + TEN;
    unsigned short* vth = khi + TEN;
    const size_t need = 4096 + 4*TEN*sizeof(unsigned short);     // ~16.8 MB

    mask_kernel4<<<dim3(H_*NB_), dim3(256), 0, stream>>>(q, k, siq, sik, mask);
    if (ws_size >= need) {
        prep_kernel<<<dim3(H_*NB_), dim3(256), 0, stream>>>(q, k, v, qhi, qlo, khi, vth);
        attn_fast<<<dim3(H_*NB_), dim3(256), 0, stream>>>(qhi, qlo, khi, vth, mask, out);
    } else {
        attn_v3<<<dim3(H_*NB_), dim3(256), 0, stream>>>(q, k, v, mask, out);
    }
}

// Round 8
// 148.688 us; speedup vs baseline: 1.7513x; 1.3366x over previous
//
#include <hip/hip_runtime.h>
#include <hip/hip_bf16.h>

// B=1, H=8, L=4096, D=64; 64x64 blocks; 16 samples/block. Inputs f32, output f32.
#define H_ 8
#define L_ 4096
#define D_ 64
#define NB_ 64

typedef __attribute__((ext_vector_type(8))) short bf16x8;
typedef __attribute__((ext_vector_type(4))) float f32x4;

__device__ __forceinline__ unsigned short f2bf(float x) {   // RNE f32->bf16
    unsigned u = __float_as_uint(x);
    u += 0x7fff + ((u >> 16) & 1);
    return (unsigned short)(u >> 16);
}
__device__ __forceinline__ float bf2f(unsigned short s) {
    return __uint_as_float(((unsigned)s) << 16);
}

// ---------------------------------------------------------------------------
// Preprocess: per (h, tile) build bf16 ws tensors once.
//   Qhi/Qlo row-major; Khi row-major d-chunk XOR-swizzled by (row&7);
//   Vthi transposed [d][key], key-chunk XOR-swizzled by (d&7);
//   skh/skl = sampled-K rows [h][1024][64] hi/lo, d-chunk XOR-swizzled
//   by (col&7) (B-layout for the MFMA mask kernel; col = tb*16 + t).
// ---------------------------------------------------------------------------
__global__ __launch_bounds__(256) void prep_kernel(
    const float* __restrict__ q, const float* __restrict__ k, const float* __restrict__ v,
    const int* __restrict__ sidxk,
    unsigned short* __restrict__ qhi, unsigned short* __restrict__ qlo,
    unsigned short* __restrict__ khi,
    unsigned short* __restrict__ vth,
    unsigned short* __restrict__ skh, unsigned short* __restrict__ skl)
{
    const int h  = blockIdx.x >> 6;
    const int tb = blockIdx.x & 63;
    const int tid = threadIdx.x;
    __shared__ float vst[64][68];

    const size_t te = ((size_t)(h*64 + tb)) << 12;   // tile base (elements)
    const float4* qg = (const float4*)(q + te);
    for (int i4 = tid; i4 < 1024; i4 += 256) {
        float4 t = qg[i4];
        ushort4 hi, lo;
        hi.x = f2bf(t.x); lo.x = f2bf(t.x - bf2f(hi.x));
        hi.y = f2bf(t.y); lo.y = f2bf(t.y - bf2f(hi.y));
        hi.z = f2bf(t.z); lo.z = f2bf(t.z - bf2f(hi.z));
        hi.w = f2bf(t.w); lo.w = f2bf(t.w - bf2f(hi.w));
        *(ushort4*)(qhi + te + i4*4) = hi;
        *(ushort4*)(qlo + te + i4*4) = lo;
    }
    const float4* kg = (const float4*)(k + te);
    for (int i4 = tid; i4 < 1024; i4 += 256) {
        float4 t = kg[i4];
        int r = i4 >> 4, c4 = i4 & 15;
        int sch = (c4 >> 1) ^ (r & 7);
        ushort4 hi;
        hi.x = f2bf(t.x); hi.y = f2bf(t.y); hi.z = f2bf(t.z); hi.w = f2bf(t.w);
        *(ushort4*)(khi + te + r*64 + sch*8 + (c4 & 1)*4) = hi;
    }
    // sampled-K rows for the MFMA mask: 16 rows per tile, hi/lo, swizzled
    {
        int t = tid >> 4, d4 = tid & 15;           // row t (0..15), d-quad d4
        int srow = tb*64 + sidxk[h*16 + t];        // source row in k
        float4 x = *(const float4*)(k + ((size_t)h*L_ + srow)*D_ + d4*4);
        ushort4 hi, lo;
        hi.x = f2bf(x.x); lo.x = f2bf(x.x - bf2f(hi.x));
        hi.y = f2bf(x.y); lo.y = f2bf(x.y - bf2f(hi.y));
        hi.z = f2bf(x.z); lo.z = f2bf(x.z - bf2f(hi.z));
        hi.w = f2bf(x.w); lo.w = f2bf(x.w - bf2f(hi.w));
        int sch = (d4 >> 1) ^ (t & 7);             // reader n&7 == (tb*16+t)&7 == t&7
        size_t dst = ((size_t)h*1024 + tb*16 + t)*64 + sch*8 + (d4 & 1)*4;
        *(ushort4*)(skh + dst) = hi;
        *(ushort4*)(skl + dst) = lo;
    }
    const float4* vg = (const float4*)(v + te);
    for (int i4 = tid; i4 < 1024; i4 += 256) {
        float4 t = vg[i4];
        *(float4*)&vst[i4 >> 4][(i4 & 15)*4] = t;
    }
    __syncthreads();
    for (int u = tid; u < 512; u += 256) {
        int d = u >> 3, kc8 = u & 7;
        int sch = kc8 ^ (d & 7);
        ushort4 h0, h1;
        h0.x = f2bf(vst[kc8*8+0][d]); h0.y = f2bf(vst[kc8*8+1][d]);
        h0.z = f2bf(vst[kc8*8+2][d]); h0.w = f2bf(vst[kc8*8+3][d]);
        h1.x = f2bf(vst[kc8*8+4][d]); h1.y = f2bf(vst[kc8*8+5][d]);
        h1.z = f2bf(vst[kc8*8+6][d]); h1.w = f2bf(vst[kc8*8+7][d]);
        *(ushort4*)(vth + te + d*64 + sch*8 + 0) = h0;
        *(ushort4*)(vth + te + d*64 + sch*8 + 4) = h1;
    }
}

// ---------------------------------------------------------------------------
// Kernel A (v5.1): MFMA block mask. One block per (h,qb), grid 512, 4 waves.
// ROUND-7 BUG: staging loop copied 512 bf16x8 = HALF the 128x64 chunk
// (1024 bf16x8) -> key blocks cc*8+4..7 scored against garbage LDS ->
// wrong masks (absmax 0.43). Fixed: i < 1024.
// S via EXACT hi/lo split (4 MFMAs; split residual ~2^-25 rel => f32-class,
// safe for 0.5-boundary decisions). Per 16-col tile == one key block: exp,
// 16-lane shfl row-sum, single writer into E[row][kb].
// ---------------------------------------------------------------------------
__global__ __launch_bounds__(256, 4) void mask_mfma(
    const unsigned short* __restrict__ qhi, const unsigned short* __restrict__ qlo,
    const unsigned short* __restrict__ skh, const unsigned short* __restrict__ skl,
    const int* __restrict__ sidxq,
    unsigned long long* __restrict__ maskbits)
{
    const int h    = blockIdx.x >> 6;
    const int qb   = blockIdx.x & 63;
    const int tid  = threadIdx.x;
    const int wave = tid >> 6;
    const int lane = tid & 63;
    const int l16  = lane & 15;
    const int quad = lane >> 4;

    __shared__ __align__(16) unsigned short ch[8192];   // 128 cols x 64 d hi (16 KB)
    __shared__ __align__(16) unsigned short cl[8192];   // lo                 (16 KB)
    __shared__ float E[16][64];
    __shared__ float Z[16];
    __shared__ float pooled[64];

    for (int e = tid; e < 16*64; e += 256) (&E[0][0])[e] = 0.f;

    // A-frags: m = l16 -> sampled q row iq[l16] of block qb
    const int iqr = sidxq[h*16 + l16];
    const size_t qo = (((size_t)(h*64 + qb)) << 12) + (size_t)iqr*64;
    bf16x8 qh[2], ql[2];
    qh[0] = *(const bf16x8*)(qhi + qo + quad*8);
    qh[1] = *(const bf16x8*)(qhi + qo + 32 + quad*8);
    ql[0] = *(const bf16x8*)(qlo + qo + quad*8);
    ql[1] = *(const bf16x8*)(qlo + qo + 32 + quad*8);
    __syncthreads();   // E init visible

    for (int cc = 0; cc < 8; ++cc) {
        const bf16x8* gh = (const bf16x8*)(skh + ((size_t)h*1024 + cc*128)*64);
        const bf16x8* gl = (const bf16x8*)(skl + ((size_t)h*1024 + cc*128)*64);
        for (int i = tid; i < 1024; i += 256) {   // FIX: full 1024 bf16x8 chunk
            ((bf16x8*)ch)[i] = gh[i];
            ((bf16x8*)cl)[i] = gl[i];
        }
        __syncthreads();

        #pragma unroll
        for (int tt = 0; tt < 2; ++tt) {
            const int kb = cc*8 + wave*2 + tt;
            const int nb = (wave*2 + tt)*16;
            f32x4 sacc = (f32x4){0.f, 0.f, 0.f, 0.f};
            #pragma unroll
            for (int kc = 0; kc < 2; ++kc) {
                const int off = (nb + l16)*64 + (((kc*4 + quad) ^ (l16 & 7))*8);
                bf16x8 kh = *(const bf16x8*)&ch[off];
                bf16x8 kl = *(const bf16x8*)&cl[off];
                sacc = __builtin_amdgcn_mfma_f32_16x16x32_bf16(qh[kc], kh, sacc, 0, 0, 0);
                sacc = __builtin_amdgcn_mfma_f32_16x16x32_bf16(qh[kc], kl, sacc, 0, 0, 0);
                sacc = __builtin_amdgcn_mfma_f32_16x16x32_bf16(ql[kc], kh, sacc, 0, 0, 0);
                sacc = __builtin_amdgcn_mfma_f32_16x16x32_bf16(ql[kc], kl, sacc, 0, 0, 0);
            }
            #pragma unroll
            for (int r = 0; r < 4; ++r) {
                float p = __expf(sacc[r] * 0.125f);   // |s|<~8: safe unshifted
                p += __shfl_xor(p, 1);
                p += __shfl_xor(p, 2);
                p += __shfl_xor(p, 4);
                p += __shfl_xor(p, 8);
                if (l16 == 0) E[quad*4 + r][kb] = p;  // single write per (row,kb)
            }
        }
        __syncthreads();
    }

    if (tid < 16) {
        float s = 0.f;
        #pragma unroll
        for (int kb = 0; kb < 64; ++kb) s += E[tid][kb];
        Z[tid] = s;
    }
    __syncthreads();
    if (tid < 64) {
        float s = 0.f;
        #pragma unroll
        for (int t = 0; t < 16; ++t) s += E[t][tid] / Z[t];
        pooled[tid] = s;
    }
    __syncthreads();
    if (tid < 64) {   // top-p 0.5, stable descending rank
        float pi = pooled[tid];
        float tot = 0.f, bef = 0.f;
        for (int j2 = 0; j2 < 64; ++j2) {
            float pj = pooled[j2];
            tot += pj;
            if (pj > pi || (pj == pi && j2 < tid)) bef += pj;
        }
        bool att = (bef / tot) < 0.5f;
        unsigned long long bits = __ballot(att);   // wave 0
        if (tid == 0) maskbits[h*64 + qb] = bits;
    }
}

// ---------------------------------------------------------------------------
// Kernel B (v6): block-sparse flash attention, FIXED-M softmax.
// Scores bounded (max |s| ~ 6.2 << 16), so p = exp(s - 16) never overflows
// and M cancels exactly in sum(pV)/sum(p). Deletes per-kb rowmax trees,
// al/m state, and oacc rescale. l accumulates as per-lane register
// partials; one shfl tree at the end.
// ---------------------------------------------------------------------------
__global__ __launch_bounds__(256, 2) void attn_fast(
    const unsigned short* __restrict__ qhi, const unsigned short* __restrict__ qlo,
    const unsigned short* __restrict__ khi,
    const unsigned short* __restrict__ vth,
    const unsigned long long* __restrict__ maskbits,
    float* __restrict__ out)
{
    const int h    = blockIdx.x >> 6;
    const int qb   = blockIdx.x & 63;
    const int tid  = threadIdx.x;
    const int wave = tid >> 6;
    const int lane = tid & 63;
    const int l16  = lane & 15;
    const int quad = lane >> 4;

    __shared__ __align__(16) unsigned short bufK[2][4096];
    __shared__ __align__(16) unsigned short bufVh[2][4096];
    __shared__ __align__(16) unsigned short ps[4][16][80];

    const size_t qoff = (((size_t)(h*64 + qb)) << 12) + (size_t)(wave*16 + l16)*64;
    bf16x8 qfh[2], qfl[2];
    qfh[0] = *(const bf16x8*)(qhi + qoff + quad*8);
    qfh[1] = *(const bf16x8*)(qhi + qoff + 32 + quad*8);
    qfl[0] = *(const bf16x8*)(qlo + qoff + quad*8);
    qfl[1] = *(const bf16x8*)(qlo + qoff + 32 + quad*8);

    const unsigned long long bm = maskbits[(h << 6) + qb];

    float lpart[4];   // per-lane partial of l over this lane's 4 columns
    f32x4 oacc[4];
    #pragma unroll
    for (int r = 0; r < 4; ++r) lpart[r] = 0.f;
    #pragma unroll
    for (int t = 0; t < 4; ++t) oacc[t] = (f32x4){0.f, 0.f, 0.f, 0.f};

    bf16x8 rK[2], rVh[2];
    auto stage_load = [&](int kb) {
        const size_t tb = ((size_t)(h*64 + kb)) << 12;
        const bf16x8* gk = (const bf16x8*)(khi + tb);
        const bf16x8* gh = (const bf16x8*)(vth + tb);
        rK[0]  = gk[tid]; rK[1]  = gk[tid + 256];
        rVh[0] = gh[tid]; rVh[1] = gh[tid + 256];
    };
    auto stage_write = [&](int b) {
        ((bf16x8*)&bufK [b][0])[tid] = rK[0];  ((bf16x8*)&bufK [b][0])[tid+256] = rK[1];
        ((bf16x8*)&bufVh[b][0])[tid] = rVh[0]; ((bf16x8*)&bufVh[b][0])[tid+256] = rVh[1];
    };

    auto compute = [&](int b) {
        f32x4 sacc[4];
        #pragma unroll
        for (int t = 0; t < 4; ++t) sacc[t] = (f32x4){0.f, 0.f, 0.f, 0.f};
        #pragma unroll
        for (int t = 0; t < 4; ++t) {
            #pragma unroll
            for (int kc = 0; kc < 2; ++kc) {
                bf16x8 kf = *(const bf16x8*)&bufK[b][(t*16 + l16)*64 + (((kc*4 + quad) ^ (l16 & 7))*8)];
                sacc[t] = __builtin_amdgcn_mfma_f32_16x16x32_bf16(qfh[kc], kf, sacc[t], 0, 0, 0);
                sacc[t] = __builtin_amdgcn_mfma_f32_16x16x32_bf16(qfl[kc], kf, sacc[t], 0, 0, 0);
            }
        }
        // p = exp(s*0.125 - 16); no rowmax, no rescale (M constant, cancels)
        #pragma unroll
        for (int t = 0; t < 4; ++t) {
            #pragma unroll
            for (int r = 0; r < 4; ++r) {
                float p = __expf(fmaf(sacc[t][r], 0.125f, -16.0f));
                unsigned short pb = f2bf(p);
                ps[wave][quad*4 + r][t*16 + l16] = pb;
                lpart[r] += bf2f(pb);   // l from ROUNDED p: self-consistent
            }
        }
        bf16x8 pf[2];
        #pragma unroll
        for (int kc = 0; kc < 2; ++kc)
            pf[kc] = *(const bf16x8*)&ps[wave][l16][kc*32 + quad*8];
        #pragma unroll
        for (int t = 0; t < 4; ++t) {
            #pragma unroll
            for (int kc = 0; kc < 2; ++kc) {
                bf16x8 vh = *(const bf16x8*)&bufVh[b][(t*16 + l16)*64 + (((kc*4 + quad) ^ (l16 & 7))*8)];
                oacc[t] = __builtin_amdgcn_mfma_f32_16x16x32_bf16(pf[kc], vh, oacc[t], 0, 0, 0);
            }
        }
    };

    unsigned long long rem = bm;
    int kb0 = (int)__builtin_ctzll(rem); rem &= rem - 1;
    stage_load(kb0);
    stage_write(0);
    int cur = 0;
    for (;;) {
        int nxt = -1;
        if (rem) { nxt = (int)__builtin_ctzll(rem); rem &= rem - 1; stage_load(nxt); }
        __syncthreads();
        compute(cur);
        if (nxt < 0) break;
        stage_write(cur ^ 1);
        cur ^= 1;
    }

    // final l: reduce lane partials over the 16-lane column group
    #pragma unroll
    for (int off = 1; off < 16; off <<= 1)
        #pragma unroll
        for (int r = 0; r < 4; ++r)
            lpart[r] += __shfl_xor(lpart[r], off);

    float* og = out + ((size_t)h*L_ + (size_t)qb*64)*D_ + (size_t)(wave*16 + quad*4)*D_;
    #pragma unroll
    for (int r = 0; r < 4; ++r) {
        float inv = 1.f / lpart[r];
        #pragma unroll
        for (int t = 0; t < 4; ++t)
            og[(size_t)r*D_ + t*16 + l16] = oacc[t][r] * inv;
    }
}

// ---------------------------------------------------------------------------
// Fallback path (round-6, proven): mask_kernel4 + attn_v3, only if ws small.
// ---------------------------------------------------------------------------
__global__ __launch_bounds__(256, 4) void mask_kernel4(
    const float* __restrict__ q, const float* __restrict__ k,
    const int* __restrict__ sidxq, const int* __restrict__ sidxk,
    unsigned long long* __restrict__ maskbits)
{
    const int h   = blockIdx.x >> 6;
    const int qb  = blockIdx.x & 63;
    const int tid = threadIdx.x;
    const int rg  = tid >> 5;
    const int cg  = tid & 31;

    __shared__ float sq[16][68];
    __shared__ float skc[128][68];
    __shared__ float E[16][64];
    __shared__ float Z[16];
    __shared__ float pooled[64];
    __shared__ int iq[16], ik[16];

    if (tid < 16) { iq[tid] = sidxq[h*16 + tid]; ik[tid] = sidxk[h*16 + tid]; }
    for (int e = tid; e < 16*64; e += 256) (&E[0][0])[e] = 0.f;
    __syncthreads();
    {
        int j = tid >> 4, d4 = tid & 15;
        int grow = h*L_ + qb*64 + iq[j];
        *(float4*)&sq[j][d4*4] = *(const float4*)(q + (size_t)grow*D_ + d4*4);
    }
    for (int cc = 0; cc < 8; ++cc) {
        for (int i = tid; i < 2048; i += 256) {
            int col = i >> 4, d4 = i & 15;
            int colg = cc*128 + col;
            int grow = h*L_ + (colg >> 4)*64 + ik[colg & 15];
            *(float4*)&skc[col][d4*4] = *(const float4*)(k + (size_t)grow*D_ + d4*4);
        }
        __syncthreads();
        float acc[2][4] = {{0.f,0.f,0.f,0.f},{0.f,0.f,0.f,0.f}};
        #pragma unroll 4
        for (int d4 = 0; d4 < 16; ++d4) {
            float4 qv0 = *(const float4*)&sq[rg*2 + 0][d4*4];
            float4 qv1 = *(const float4*)&sq[rg*2 + 1][d4*4];
            #pragma unroll
            for (int j = 0; j < 4; ++j) {
                float4 kv = *(const float4*)&skc[cg + 32*j][d4*4];
                acc[0][j] += qv0.x*kv.x + qv0.y*kv.y + qv0.z*kv.z + qv0.w*kv.w;
                acc[1][j] += qv1.x*kv.x + qv1.y*kv.y + qv1.z*kv.z + qv1.w*kv.w;
            }
        }
        #pragma unroll
        for (int j = 0; j < 4; ++j) {
            int kb = cc*8 + (cg >> 4) + 2*j;
            #pragma unroll
            for (int i = 0; i < 2; ++i) {
                float p = __expf(acc[i][j] * 0.125f);
                p += __shfl_xor(p, 1);
                p += __shfl_xor(p, 2);
                p += __shfl_xor(p, 4);
                p += __shfl_xor(p, 8);
                if ((cg & 15) == 0) E[rg*2 + i][kb] += p;
            }
        }
        __syncthreads();
    }
    if (tid < 16) {
        float s = 0.f;
        #pragma unroll
        for (int kb = 0; kb < 64; ++kb) s += E[tid][kb];
        Z[tid] = s;
    }
    __syncthreads();
    if (tid < 64) {
        float s = 0.f;
        #pragma unroll
        for (int t = 0; t < 16; ++t) s += E[t][tid] / Z[t];
        pooled[tid] = s;
    }
    __syncthreads();
    if (tid < 64) {
        float pi = pooled[tid];
        float tot = 0.f, bef = 0.f;
        for (int j2 = 0; j2 < 64; ++j2) {
            float pj = pooled[j2];
            tot += pj;
            if (pj > pi || (pj == pi && j2 < tid)) bef += pj;
        }
        bool att = (bef / tot) < 0.5f;
        unsigned long long bits = __ballot(att);
        if (tid == 0) maskbits[h*64 + qb] = bits;
    }
}

__global__ __launch_bounds__(256, 3) void attn_v3(
    const float* __restrict__ q, const float* __restrict__ k, const float* __restrict__ v,
    const unsigned long long* __restrict__ maskbits, float* __restrict__ out)
{
    const int h = blockIdx.x >> 6, qb = blockIdx.x & 63;
    const int tid = threadIdx.x, wave = tid >> 6, lane = tid & 63;
    const int l16 = lane & 15, quad = lane >> 4;
    __shared__ __align__(16) unsigned short ks_hi[64][72];
    __shared__ __align__(16) unsigned short ks_lo[64][72];
    __shared__ __align__(16) unsigned short vt_hi[64][72];
    __shared__ __align__(16) unsigned short vt_lo[64][72];
    __shared__ __align__(16) unsigned short ps[4][16][72];

    const float4* qg = (const float4*)(q + ((size_t)h*L_ + (size_t)qb*64)*D_);
    for (int i4 = tid; i4 < 1024; i4 += 256) {
        float4 t = qg[i4];
        int r = i4 >> 4, c = (i4 & 15) << 2;
        ushort4 hi, lo;
        hi.x = f2bf(t.x); lo.x = f2bf(t.x - bf2f(hi.x));
        hi.y = f2bf(t.y); lo.y = f2bf(t.y - bf2f(hi.y));
        hi.z = f2bf(t.z); lo.z = f2bf(t.z - bf2f(hi.z));
        hi.w = f2bf(t.w); lo.w = f2bf(t.w - bf2f(hi.w));
        *(ushort4*)&ks_hi[r][c] = hi;
        *(ushort4*)&ks_lo[r][c] = lo;
    }
    const unsigned long long bm = maskbits[(h << 6) + qb];
    __syncthreads();
    bf16x8 qhi2[2], qlo2[2];
    #pragma unroll
    for (int kc = 0; kc < 2; ++kc) {
        qhi2[kc] = *(const bf16x8*)&ks_hi[wave*16 + l16][kc*32 + quad*8];
        qlo2[kc] = *(const bf16x8*)&ks_lo[wave*16 + l16][kc*32 + quad*8];
    }
    __syncthreads();
    float m_i[4], l_i[4];
    f32x4 oacc[4];
    #pragma unroll
    for (int r = 0; r < 4; ++r) { m_i[r] = -1e30f; l_i[r] = 0.f; }
    #pragma unroll
    for (int t = 0; t < 4; ++t) oacc[t] = (f32x4){0.f, 0.f, 0.f, 0.f};
    for (int kb = 0; kb < 64; ++kb) {
        if (!((bm >> kb) & 1ull)) continue;
        const float4* kg = (const float4*)(k + ((size_t)h*L_ + (size_t)kb*64)*D_);
        const float*  vg = v + ((size_t)h*L_ + (size_t)kb*64)*D_;
        for (int i4 = tid; i4 < 1024; i4 += 256) {
            float4 t = kg[i4];
            int r = i4 >> 4, c = (i4 & 15) << 2;
            ushort4 hi, lo;
            hi.x = f2bf(t.x); lo.x = f2bf(t.x - bf2f(hi.x));
            hi.y = f2bf(t.y); lo.y = f2bf(t.y - bf2f(hi.y));
            hi.z = f2bf(t.z); lo.z = f2bf(t.z - bf2f(hi.z));
            hi.w = f2bf(t.w); lo.w = f2bf(t.w - bf2f(hi.w));
            *(ushort4*)&ks_hi[r][c] = hi;
            *(ushort4*)&ks_lo[r][c] = lo;
        }
        for (int tsk = tid; tsk < 512; tsk += 256) {
            int rp = tsk >> 4;
            int c  = (tsk & 15) << 2;
            float4 a0 = *(const float4*)(vg + (size_t)(2*rp)*D_ + c);
            float4 a1 = *(const float4*)(vg + (size_t)(2*rp+1)*D_ + c);
            #pragma unroll
            for (int j = 0; j < 4; ++j) {
                float x0 = (j==0)?a0.x:(j==1)?a0.y:(j==2)?a0.z:a0.w;
                float x1 = (j==0)?a1.x:(j==1)?a1.y:(j==2)?a1.z:a1.w;
                unsigned short h0 = f2bf(x0), h1b = f2bf(x1);
                *(unsigned*)&vt_hi[c+j][2*rp] = (unsigned)h0 | ((unsigned)h1b << 16);
                unsigned short lo0 = f2bf(x0 - bf2f(h0)), lo1 = f2bf(x1 - bf2f(h1b));
                *(unsigned*)&vt_lo[c+j][2*rp] = (unsigned)lo0 | ((unsigned)lo1 << 16);
            }
        }
        __syncthreads();
        f32x4 sacc[4];
        #pragma unroll
        for (int t = 0; t < 4; ++t) sacc[t] = (f32x4){0.f, 0.f, 0.f, 0.f};
        #pragma unroll
        for (int t = 0; t < 4; ++t) {
            #pragma unroll
            for (int kc = 0; kc < 2; ++kc) {
                bf16x8 khi2 = *(const bf16x8*)&ks_hi[t*16 + l16][kc*32 + quad*8];
                bf16x8 klo2 = *(const bf16x8*)&ks_lo[t*16 + l16][kc*32 + quad*8];
                sacc[t] = __builtin_amdgcn_mfma_f32_16x16x32_bf16(qhi2[kc], khi2, sacc[t], 0, 0, 0);
                sacc[t] = __builtin_amdgcn_mfma_f32_16x16x32_bf16(qhi2[kc], klo2, sacc[t], 0, 0, 0);
                sacc[t] = __builtin_amdgcn_mfma_f32_16x16x32_bf16(qlo2[kc], khi2, sacc[t], 0, 0, 0);
            }
        }
        #pragma unroll
        for (int t = 0; t < 4; ++t) sacc[t] *= 0.125f;
        float rowmax[4];
        #pragma unroll
        for (int r = 0; r < 4; ++r)
            rowmax[r] = fmaxf(fmaxf(sacc[0][r], sacc[1][r]), fmaxf(sacc[2][r], sacc[3][r]));
        #pragma unroll
        for (int off = 1; off < 16; off <<= 1)
            #pragma unroll
            for (int r = 0; r < 4; ++r)
                rowmax[r] = fmaxf(rowmax[r], __shfl_xor(rowmax[r], off));
        float al[4], rs[4];
        #pragma unroll
        for (int r = 0; r < 4; ++r) {
            float mnew = fmaxf(m_i[r], rowmax[r]);
            al[r] = __expf(m_i[r] - mnew);
            m_i[r] = mnew;
            float acc = 0.f;
            #pragma unroll
            for (int t = 0; t < 4; ++t) {
                float p = __expf(sacc[t][r] - mnew);
                unsigned short pb = f2bf(p);
                ps[wave][quad*4 + r][t*16 + l16] = pb;
                acc += bf2f(pb);
            }
            rs[r] = acc;
        }
        #pragma unroll
        for (int off = 1; off < 16; off <<= 1)
            #pragma unroll
            for (int r = 0; r < 4; ++r)
                rs[r] += __shfl_xor(rs[r], off);
        #pragma unroll
        for (int r = 0; r < 4; ++r) l_i[r] = l_i[r] * al[r] + rs[r];
        #pragma unroll
        for (int t = 0; t < 4; ++t)
            #pragma unroll
            for (int r = 0; r < 4; ++r) oacc[t][r] *= al[r];
        bf16x8 pf[2];
        #pragma unroll
        for (int kc = 0; kc < 2; ++kc)
            pf[kc] = *(const bf16x8*)&ps[wave][l16][kc*32 + quad*8];
        #pragma unroll
        for (int t = 0; t < 4; ++t) {
            #pragma unroll
            for (int kc = 0; kc < 2; ++kc) {
                bf16x8 vhif = *(const bf16x8*)&vt_hi[t*16 + l16][kc*32 + quad*8];
                bf16x8 vlof = *(const bf16x8*)&vt_lo[t*16 + l16][kc*32 + quad*8];
                oacc[t] = __builtin_amdgcn_mfma_f32_16x16x32_bf16(pf[kc], vhif, oacc[t], 0, 0, 0);
                oacc[t] = __builtin_amdgcn_mfma_f32_16x16x32_bf16(pf[kc], vlof, oacc[t], 0, 0, 0);
            }
        }
        __syncthreads();
    }
    float* og = out + ((size_t)h*L_ + (size_t)qb*64)*D_ + (size_t)(wave*16 + quad*4)*D_;
    #pragma unroll
    for (int r = 0; r < 4; ++r) {
        float inv = 1.f / l_i[r];
        #pragma unroll
        for (int t = 0; t < 4; ++t)
            og[(size_t)r*D_ + t*16 + l16] = oacc[t][r] * inv;
    }
}

extern "C" void kernel_launch(void* const* d_in, const int* in_sizes, int n_in,
                              void* d_out, int out_size, void* d_ws, size_t ws_size,
                              hipStream_t stream) {
    const float* q = (const float*)d_in[0];
    const float* k = (const float*)d_in[1];
    const float* v = (const float*)d_in[2];
    const int* siq = (const int*)d_in[3];
    const int* sik = (const int*)d_in[4];
    float* out = (float*)d_out;

    char* ws = (char*)d_ws;
    unsigned long long* mask = (unsigned long long*)ws;          // 4 KB
    const size_t TEN = (size_t)H_*L_*D_;                         // 2,097,152 elems
    const size_t SKN = (size_t)H_*1024*64;                       //   524,288 elems
    unsigned short* qhi = (unsigned short*)(ws + 4096);
    unsigned short* qlo = qhi + TEN;
    unsigned short* khi = qlo + TEN;
    unsigned short* vth = khi + TEN;
    unsigned short* skh = vth + TEN;
    unsigned short* skl = skh + SKN;
    const size_t need = 4096 + (4*TEN + 2*SKN)*sizeof(unsigned short);  // ~18.9 MB

    if (ws_size >= need) {
        prep_kernel<<<dim3(H_*NB_), dim3(256), 0, stream>>>(q, k, v, sik, qhi, qlo, khi, vth, skh, skl);
        mask_mfma<<<dim3(H_*NB_), dim3(256), 0, stream>>>(qhi, qlo, skh, skl, siq, mask);
        attn_fast<<<dim3(H_*NB_), dim3(256), 0, stream>>>(qhi, qlo, khi, vth, mask, out);
    } else {
        mask_kernel4<<<dim3(H_*NB_), dim3(256), 0, stream>>>(q, k, siq, sik, mask);
        attn_v3<<<dim3(H_*NB_), dim3(256), 0, stream>>>(q, k, v, mask, out);
    }
}

// Round 9
// 147.994 us; speedup vs baseline: 1.7595x; 1.0047x over previous
//
#include <hip/hip_runtime.h>
#include <hip/hip_bf16.h>

// B=1, H=8, L=4096, D=64; 64x64 blocks; 16 samples/block. Inputs f32, output f32.
#define H_ 8
#define L_ 4096
#define D_ 64
#define NB_ 64

typedef __attribute__((ext_vector_type(8))) short bf16x8;
typedef __attribute__((ext_vector_type(4))) float f32x4;

__device__ __forceinline__ unsigned short f2bf(float x) {   // RNE f32->bf16
    unsigned u = __float_as_uint(x);
    u += 0x7fff + ((u >> 16) & 1);
    return (unsigned short)(u >> 16);
}
__device__ __forceinline__ float bf2f(unsigned short s) {
    return __uint_as_float(((unsigned)s) << 16);
}
// async 16B global -> LDS DMA (no VGPR round-trip, no wave-issued ds_write)
__device__ __forceinline__ void gload_lds16(const unsigned short* g, unsigned short* l) {
    __builtin_amdgcn_global_load_lds(
        (const __attribute__((address_space(1))) unsigned int*)(const void*)g,
        (__attribute__((address_space(3))) unsigned int*)(void*)l,
        16, 0, 0);
}

// ---------------------------------------------------------------------------
// Preprocess: per (h, tile) build bf16 ws tensors once.
//   Qhi/Qlo row-major.
//   Khi row-major, d-chunk XOR-swizzled by ((row>>2)&7)  [ROUND 9: was row&7 —
//     attn S-tiles now read keys l16*4+t, so swizzle must vary with key>>2].
//   Vthi transposed [d][key], key-chunk XOR-swizzled by (d&7) (unchanged).
//   skh/skl sampled-K rows, d-chunk XOR-swizzled by (col&7) (unchanged).
// ---------------------------------------------------------------------------
__global__ __launch_bounds__(256) void prep_kernel(
    const float* __restrict__ q, const float* __restrict__ k, const float* __restrict__ v,
    const int* __restrict__ sidxk,
    unsigned short* __restrict__ qhi, unsigned short* __restrict__ qlo,
    unsigned short* __restrict__ khi,
    unsigned short* __restrict__ vth,
    unsigned short* __restrict__ skh, unsigned short* __restrict__ skl)
{
    const int h  = blockIdx.x >> 6;
    const int tb = blockIdx.x & 63;
    const int tid = threadIdx.x;
    __shared__ float vst[64][68];

    const size_t te = ((size_t)(h*64 + tb)) << 12;   // tile base (elements)
    const float4* qg = (const float4*)(q + te);
    for (int i4 = tid; i4 < 1024; i4 += 256) {
        float4 t = qg[i4];
        ushort4 hi, lo;
        hi.x = f2bf(t.x); lo.x = f2bf(t.x - bf2f(hi.x));
        hi.y = f2bf(t.y); lo.y = f2bf(t.y - bf2f(hi.y));
        hi.z = f2bf(t.z); lo.z = f2bf(t.z - bf2f(hi.z));
        hi.w = f2bf(t.w); lo.w = f2bf(t.w - bf2f(hi.w));
        *(ushort4*)(qhi + te + i4*4) = hi;
        *(ushort4*)(qlo + te + i4*4) = lo;
    }
    const float4* kg = (const float4*)(k + te);
    for (int i4 = tid; i4 < 1024; i4 += 256) {
        float4 t = kg[i4];
        int r = i4 >> 4, c4 = i4 & 15;
        int sch = (c4 >> 1) ^ ((r >> 2) & 7);   // ROUND 9 swizzle
        ushort4 hi;
        hi.x = f2bf(t.x); hi.y = f2bf(t.y); hi.z = f2bf(t.z); hi.w = f2bf(t.w);
        *(ushort4*)(khi + te + r*64 + sch*8 + (c4 & 1)*4) = hi;
    }
    // sampled-K rows for the MFMA mask (unchanged)
    {
        int t = tid >> 4, d4 = tid & 15;
        int srow = tb*64 + sidxk[h*16 + t];
        float4 x = *(const float4*)(k + ((size_t)h*L_ + srow)*D_ + d4*4);
        ushort4 hi, lo;
        hi.x = f2bf(x.x); lo.x = f2bf(x.x - bf2f(hi.x));
        hi.y = f2bf(x.y); lo.y = f2bf(x.y - bf2f(hi.y));
        hi.z = f2bf(x.z); lo.z = f2bf(x.z - bf2f(hi.z));
        hi.w = f2bf(x.w); lo.w = f2bf(x.w - bf2f(hi.w));
        int sch = (d4 >> 1) ^ (t & 7);
        size_t dst = ((size_t)h*1024 + tb*16 + t)*64 + sch*8 + (d4 & 1)*4;
        *(ushort4*)(skh + dst) = hi;
        *(ushort4*)(skl + dst) = lo;
    }
    const float4* vg = (const float4*)(v + te);
    for (int i4 = tid; i4 < 1024; i4 += 256) {
        float4 t = vg[i4];
        *(float4*)&vst[i4 >> 4][(i4 & 15)*4] = t;
    }
    __syncthreads();
    for (int u = tid; u < 512; u += 256) {
        int d = u >> 3, kc8 = u & 7;
        int sch = kc8 ^ (d & 7);
        ushort4 h0, h1;
        h0.x = f2bf(vst[kc8*8+0][d]); h0.y = f2bf(vst[kc8*8+1][d]);
        h0.z = f2bf(vst[kc8*8+2][d]); h0.w = f2bf(vst[kc8*8+3][d]);
        h1.x = f2bf(vst[kc8*8+4][d]); h1.y = f2bf(vst[kc8*8+5][d]);
        h1.z = f2bf(vst[kc8*8+6][d]); h1.w = f2bf(vst[kc8*8+7][d]);
        *(ushort4*)(vth + te + d*64 + sch*8 + 0) = h0;
        *(ushort4*)(vth + te + d*64 + sch*8 + 4) = h1;
    }
}

// ---------------------------------------------------------------------------
// Kernel A (v5.1, unchanged from round 8): MFMA block mask.
// ---------------------------------------------------------------------------
__global__ __launch_bounds__(256, 4) void mask_mfma(
    const unsigned short* __restrict__ qhi, const unsigned short* __restrict__ qlo,
    const unsigned short* __restrict__ skh, const unsigned short* __restrict__ skl,
    const int* __restrict__ sidxq,
    unsigned long long* __restrict__ maskbits)
{
    const int h    = blockIdx.x >> 6;
    const int qb   = blockIdx.x & 63;
    const int tid  = threadIdx.x;
    const int wave = tid >> 6;
    const int lane = tid & 63;
    const int l16  = lane & 15;
    const int quad = lane >> 4;

    __shared__ __align__(16) unsigned short ch[8192];
    __shared__ __align__(16) unsigned short cl[8192];
    __shared__ float E[16][64];
    __shared__ float Z[16];
    __shared__ float pooled[64];

    for (int e = tid; e < 16*64; e += 256) (&E[0][0])[e] = 0.f;

    const int iqr = sidxq[h*16 + l16];
    const size_t qo = (((size_t)(h*64 + qb)) << 12) + (size_t)iqr*64;
    bf16x8 qh[2], ql[2];
    qh[0] = *(const bf16x8*)(qhi + qo + quad*8);
    qh[1] = *(const bf16x8*)(qhi + qo + 32 + quad*8);
    ql[0] = *(const bf16x8*)(qlo + qo + quad*8);
    ql[1] = *(const bf16x8*)(qlo + qo + 32 + quad*8);
    __syncthreads();

    for (int cc = 0; cc < 8; ++cc) {
        const bf16x8* gh = (const bf16x8*)(skh + ((size_t)h*1024 + cc*128)*64);
        const bf16x8* gl = (const bf16x8*)(skl + ((size_t)h*1024 + cc*128)*64);
        for (int i = tid; i < 1024; i += 256) {
            ((bf16x8*)ch)[i] = gh[i];
            ((bf16x8*)cl)[i] = gl[i];
        }
        __syncthreads();

        #pragma unroll
        for (int tt = 0; tt < 2; ++tt) {
            const int kb = cc*8 + wave*2 + tt;
            const int nb = (wave*2 + tt)*16;
            f32x4 sacc = (f32x4){0.f, 0.f, 0.f, 0.f};
            #pragma unroll
            for (int kc = 0; kc < 2; ++kc) {
                const int off = (nb + l16)*64 + (((kc*4 + quad) ^ (l16 & 7))*8);
                bf16x8 kh = *(const bf16x8*)&ch[off];
                bf16x8 kl = *(const bf16x8*)&cl[off];
                sacc = __builtin_amdgcn_mfma_f32_16x16x32_bf16(qh[kc], kh, sacc, 0, 0, 0);
                sacc = __builtin_amdgcn_mfma_f32_16x16x32_bf16(qh[kc], kl, sacc, 0, 0, 0);
                sacc = __builtin_amdgcn_mfma_f32_16x16x32_bf16(ql[kc], kh, sacc, 0, 0, 0);
                sacc = __builtin_amdgcn_mfma_f32_16x16x32_bf16(ql[kc], kl, sacc, 0, 0, 0);
            }
            #pragma unroll
            for (int r = 0; r < 4; ++r) {
                float p = __expf(sacc[r] * 0.125f);
                p += __shfl_xor(p, 1);
                p += __shfl_xor(p, 2);
                p += __shfl_xor(p, 4);
                p += __shfl_xor(p, 8);
                if (l16 == 0) E[quad*4 + r][kb] = p;
            }
        }
        __syncthreads();
    }

    if (tid < 16) {
        float s = 0.f;
        #pragma unroll
        for (int kb = 0; kb < 64; ++kb) s += E[tid][kb];
        Z[tid] = s;
    }
    __syncthreads();
    if (tid < 64) {
        float s = 0.f;
        #pragma unroll
        for (int t = 0; t < 16; ++t) s += E[t][tid] / Z[t];
        pooled[tid] = s;
    }
    __syncthreads();
    if (tid < 64) {
        float pi = pooled[tid];
        float tot = 0.f, bef = 0.f;
        for (int j2 = 0; j2 < 64; ++j2) {
            float pj = pooled[j2];
            tot += pj;
            if (pj > pi || (pj == pi && j2 < tid)) bef += pj;
        }
        bool att = (bef / tot) < 0.5f;
        unsigned long long bits = __ballot(att);
        if (tid == 0) maskbits[h*64 + qb] = bits;
    }
}

// ---------------------------------------------------------------------------
// Kernel B (v7): block-sparse flash attention, fixed-M softmax.
// ROUND 9:
//  (1) Permuted-key S tiles: tile t covers keys n*4+t, so a thread's 4 P
//      values per row are CONSECUTIVE keys -> one b64 write per row
//      (was 16 scalar b16 writes). ps stride 88 shorts (16B-aligned, quads
//      offset 16 banks -> 2-way = free). PV reads ps by physical key: same
//      contiguous b128 A-frag reads as before.
//  (2) Staging via global_load_lds 16B DMA, issued AFTER the barrier so the
//      barrier's structural vmcnt(0) drain only waits on the current buffer.
//  (3) Packed bf16 convert (__float22bfloat162_rn); l accumulated from the
//      stored bits -> normalization self-consistent.
// ---------------------------------------------------------------------------
__global__ __launch_bounds__(256, 2) void attn_fast(
    const unsigned short* __restrict__ qhi, const unsigned short* __restrict__ qlo,
    const unsigned short* __restrict__ khi,
    const unsigned short* __restrict__ vth,
    const unsigned long long* __restrict__ maskbits,
    float* __restrict__ out)
{
    const int h    = blockIdx.x >> 6;
    const int qb   = blockIdx.x & 63;
    const int tid  = threadIdx.x;
    const int wave = tid >> 6;
    const int lane = tid & 63;
    const int l16  = lane & 15;
    const int quad = lane >> 4;

    __shared__ __align__(16) unsigned short bufK[2][4096];
    __shared__ __align__(16) unsigned short bufVh[2][4096];
    __shared__ __align__(16) unsigned short ps[4][16][88];

    const size_t qoff = (((size_t)(h*64 + qb)) << 12) + (size_t)(wave*16 + l16)*64;
    bf16x8 qfh[2], qfl[2];
    qfh[0] = *(const bf16x8*)(qhi + qoff + quad*8);
    qfh[1] = *(const bf16x8*)(qhi + qoff + 32 + quad*8);
    qfl[0] = *(const bf16x8*)(qlo + qoff + quad*8);
    qfl[1] = *(const bf16x8*)(qlo + qoff + 32 + quad*8);

    const unsigned long long bm = maskbits[(h << 6) + qb];

    float lpart[4];
    f32x4 oacc[4];
    #pragma unroll
    for (int r = 0; r < 4; ++r) lpart[r] = 0.f;
    #pragma unroll
    for (int t = 0; t < 4; ++t) oacc[t] = (f32x4){0.f, 0.f, 0.f, 0.f};

    auto dma_stage = [&](int kb, int b) {
        const size_t tb = ((size_t)(h*64 + kb)) << 12;
        gload_lds16(khi + tb + tid*8,         &bufK [b][tid*8]);
        gload_lds16(khi + tb + (tid+256)*8,   &bufK [b][(tid+256)*8]);
        gload_lds16(vth + tb + tid*8,         &bufVh[b][tid*8]);
        gload_lds16(vth + tb + (tid+256)*8,   &bufVh[b][(tid+256)*8]);
    };

    auto compute = [&](int b) {
        f32x4 sacc[4];
        #pragma unroll
        for (int t = 0; t < 4; ++t) sacc[t] = (f32x4){0.f, 0.f, 0.f, 0.f};
        // S: tile t covers keys l16*4+t (permuted); swizzle ^(l16&7) matches
        // prep's ^((key>>2)&7) since (l16*4+t)>>2 == l16 for t<4.
        #pragma unroll
        for (int t = 0; t < 4; ++t) {
            #pragma unroll
            for (int kc = 0; kc < 2; ++kc) {
                bf16x8 kf = *(const bf16x8*)&bufK[b][(l16*4 + t)*64 + (((kc*4 + quad) ^ (l16 & 7))*8)];
                sacc[t] = __builtin_amdgcn_mfma_f32_16x16x32_bf16(qfh[kc], kf, sacc[t], 0, 0, 0);
                sacc[t] = __builtin_amdgcn_mfma_f32_16x16x32_bf16(qfl[kc], kf, sacc[t], 0, 0, 0);
            }
        }
        // p = exp(s*0.125 - 16); row = quad*4+r, keys l16*4+0..3 -> b64 write
        #pragma unroll
        for (int r = 0; r < 4; ++r) {
            float p0 = __expf(fmaf(sacc[0][r], 0.125f, -16.0f));
            float p1 = __expf(fmaf(sacc[1][r], 0.125f, -16.0f));
            float p2 = __expf(fmaf(sacc[2][r], 0.125f, -16.0f));
            float p3 = __expf(fmaf(sacc[3][r], 0.125f, -16.0f));
            __hip_bfloat162 a01 = __float22bfloat162_rn(make_float2(p0, p1));
            __hip_bfloat162 a23 = __float22bfloat162_rn(make_float2(p2, p3));
            unsigned u01 = *(unsigned*)&a01;
            unsigned u23 = *(unsigned*)&a23;
            uint2 w; w.x = u01; w.y = u23;
            *(uint2*)&ps[wave][quad*4 + r][l16*4] = w;
            lpart[r] += (bf2f((unsigned short)(u01 & 0xffffu)) + bf2f((unsigned short)(u01 >> 16)))
                      + (bf2f((unsigned short)(u23 & 0xffffu)) + bf2f((unsigned short)(u23 >> 16)));
        }
        // PV: ps indexed by physical key -> contiguous A-frag reads
        bf16x8 pf[2];
        #pragma unroll
        for (int kc = 0; kc < 2; ++kc)
            pf[kc] = *(const bf16x8*)&ps[wave][l16][kc*32 + quad*8];
        #pragma unroll
        for (int t = 0; t < 4; ++t) {
            #pragma unroll
            for (int kc = 0; kc < 2; ++kc) {
                bf16x8 vh = *(const bf16x8*)&bufVh[b][(t*16 + l16)*64 + (((kc*4 + quad) ^ (l16 & 7))*8)];
                oacc[t] = __builtin_amdgcn_mfma_f32_16x16x32_bf16(pf[kc], vh, oacc[t], 0, 0, 0);
            }
        }
    };

    // DMA-double-buffered K-loop: barrier drains DMA(cur); DMA(nxt) issued
    // after the barrier overlaps compute(cur).
    unsigned long long rem = bm;
    int cur = 0;
    {
        int kb0 = (int)__builtin_ctzll(rem); rem &= rem - 1;
        dma_stage(kb0, 0);
    }
    for (;;) {
        __syncthreads();
        int nxt = -1;
        if (rem) { nxt = (int)__builtin_ctzll(rem); rem &= rem - 1; dma_stage(nxt, cur ^ 1); }
        compute(cur);
        if (nxt < 0) break;
        cur ^= 1;
    }

    #pragma unroll
    for (int off = 1; off < 16; off <<= 1)
        #pragma unroll
        for (int r = 0; r < 4; ++r)
            lpart[r] += __shfl_xor(lpart[r], off);

    float* og = out + ((size_t)h*L_ + (size_t)qb*64)*D_ + (size_t)(wave*16 + quad*4)*D_;
    #pragma unroll
    for (int r = 0; r < 4; ++r) {
        float inv = 1.f / lpart[r];
        #pragma unroll
        for (int t = 0; t < 4; ++t)
            og[(size_t)r*D_ + t*16 + l16] = oacc[t][r] * inv;
    }
}

// ---------------------------------------------------------------------------
// Fallback path (round-6, proven): mask_kernel4 + attn_v3, only if ws small.
// ---------------------------------------------------------------------------
__global__ __launch_bounds__(256, 4) void mask_kernel4(
    const float* __restrict__ q, const float* __restrict__ k,
    const int* __restrict__ sidxq, const int* __restrict__ sidxk,
    unsigned long long* __restrict__ maskbits)
{
    const int h   = blockIdx.x >> 6;
    const int qb  = blockIdx.x & 63;
    const int tid = threadIdx.x;
    const int rg  = tid >> 5;
    const int cg  = tid & 31;

    __shared__ float sq[16][68];
    __shared__ float skc[128][68];
    __shared__ float E[16][64];
    __shared__ float Z[16];
    __shared__ float pooled[64];
    __shared__ int iq[16], ik[16];

    if (tid < 16) { iq[tid] = sidxq[h*16 + tid]; ik[tid] = sidxk[h*16 + tid]; }
    for (int e = tid; e < 16*64; e += 256) (&E[0][0])[e] = 0.f;
    __syncthreads();
    {
        int j = tid >> 4, d4 = tid & 15;
        int grow = h*L_ + qb*64 + iq[j];
        *(float4*)&sq[j][d4*4] = *(const float4*)(q + (size_t)grow*D_ + d4*4);
    }
    for (int cc = 0; cc < 8; ++cc) {
        for (int i = tid; i < 2048; i += 256) {
            int col = i >> 4, d4 = i & 15;
            int colg = cc*128 + col;
            int grow = h*L_ + (colg >> 4)*64 + ik[colg & 15];
            *(float4*)&skc[col][d4*4] = *(const float4*)(k + (size_t)grow*D_ + d4*4);
        }
        __syncthreads();
        float acc[2][4] = {{0.f,0.f,0.f,0.f},{0.f,0.f,0.f,0.f}};
        #pragma unroll 4
        for (int d4 = 0; d4 < 16; ++d4) {
            float4 qv0 = *(const float4*)&sq[rg*2 + 0][d4*4];
            float4 qv1 = *(const float4*)&sq[rg*2 + 1][d4*4];
            #pragma unroll
            for (int j = 0; j < 4; ++j) {
                float4 kv = *(const float4*)&skc[cg + 32*j][d4*4];
                acc[0][j] += qv0.x*kv.x + qv0.y*kv.y + qv0.z*kv.z + qv0.w*kv.w;
                acc[1][j] += qv1.x*kv.x + qv1.y*kv.y + qv1.z*kv.z + qv1.w*kv.w;
            }
        }
        #pragma unroll
        for (int j = 0; j < 4; ++j) {
            int kb = cc*8 + (cg >> 4) + 2*j;
            #pragma unroll
            for (int i = 0; i < 2; ++i) {
                float p = __expf(acc[i][j] * 0.125f);
                p += __shfl_xor(p, 1);
                p += __shfl_xor(p, 2);
                p += __shfl_xor(p, 4);
                p += __shfl_xor(p, 8);
                if ((cg & 15) == 0) E[rg*2 + i][kb] += p;
            }
        }
        __syncthreads();
    }
    if (tid < 16) {
        float s = 0.f;
        #pragma unroll
        for (int kb = 0; kb < 64; ++kb) s += E[tid][kb];
        Z[tid] = s;
    }
    __syncthreads();
    if (tid < 64) {
        float s = 0.f;
        #pragma unroll
        for (int t = 0; t < 16; ++t) s += E[t][tid] / Z[t];
        pooled[tid] = s;
    }
    __syncthreads();
    if (tid < 64) {
        float pi = pooled[tid];
        float tot = 0.f, bef = 0.f;
        for (int j2 = 0; j2 < 64; ++j2) {
            float pj = pooled[j2];
            tot += pj;
            if (pj > pi || (pj == pi && j2 < tid)) bef += pj;
        }
        bool att = (bef / tot) < 0.5f;
        unsigned long long bits = __ballot(att);
        if (tid == 0) maskbits[h*64 + qb] = bits;
    }
}

__global__ __launch_bounds__(256, 3) void attn_v3(
    const float* __restrict__ q, const float* __restrict__ k, const float* __restrict__ v,
    const unsigned long long* __restrict__ maskbits, float* __restrict__ out)
{
    const int h = blockIdx.x >> 6, qb = blockIdx.x & 63;
    const int tid = threadIdx.x, wave = tid >> 6, lane = tid & 63;
    const int l16 = lane & 15, quad = lane >> 4;
    __shared__ __align__(16) unsigned short ks_hi[64][72];
    __shared__ __align__(16) unsigned short ks_lo[64][72];
    __shared__ __align__(16) unsigned short vt_hi[64][72];
    __shared__ __align__(16) unsigned short vt_lo[64][72];
    __shared__ __align__(16) unsigned short ps[4][16][72];

    const float4* qg = (const float4*)(q + ((size_t)h*L_ + (size_t)qb*64)*D_);
    for (int i4 = tid; i4 < 1024; i4 += 256) {
        float4 t = qg[i4];
        int r = i4 >> 4, c = (i4 & 15) << 2;
        ushort4 hi, lo;
        hi.x = f2bf(t.x); lo.x = f2bf(t.x - bf2f(hi.x));
        hi.y = f2bf(t.y); lo.y = f2bf(t.y - bf2f(hi.y));
        hi.z = f2bf(t.z); lo.z = f2bf(t.z - bf2f(hi.z));
        hi.w = f2bf(t.w); lo.w = f2bf(t.w - bf2f(hi.w));
        *(ushort4*)&ks_hi[r][c] = hi;
        *(ushort4*)&ks_lo[r][c] = lo;
    }
    const unsigned long long bm = maskbits[(h << 6) + qb];
    __syncthreads();
    bf16x8 qhi2[2], qlo2[2];
    #pragma unroll
    for (int kc = 0; kc < 2; ++kc) {
        qhi2[kc] = *(const bf16x8*)&ks_hi[wave*16 + l16][kc*32 + quad*8];
        qlo2[kc] = *(const bf16x8*)&ks_lo[wave*16 + l16][kc*32 + quad*8];
    }
    __syncthreads();
    float m_i[4], l_i[4];
    f32x4 oacc[4];
    #pragma unroll
    for (int r = 0; r < 4; ++r) { m_i[r] = -1e30f; l_i[r] = 0.f; }
    #pragma unroll
    for (int t = 0; t < 4; ++t) oacc[t] = (f32x4){0.f, 0.f, 0.f, 0.f};
    for (int kb = 0; kb < 64; ++kb) {
        if (!((bm >> kb) & 1ull)) continue;
        const float4* kg = (const float4*)(k + ((size_t)h*L_ + (size_t)kb*64)*D_);
        const float*  vg = v + ((size_t)h*L_ + (size_t)kb*64)*D_;
        for (int i4 = tid; i4 < 1024; i4 += 256) {
            float4 t = kg[i4];
            int r = i4 >> 4, c = (i4 & 15) << 2;
            ushort4 hi, lo;
            hi.x = f2bf(t.x); lo.x = f2bf(t.x - bf2f(hi.x));
            hi.y = f2bf(t.y); lo.y = f2bf(t.y - bf2f(hi.y));
            hi.z = f2bf(t.z); lo.z = f2bf(t.z - bf2f(hi.z));
            hi.w = f2bf(t.w); lo.w = f2bf(t.w - bf2f(hi.w));
            *(ushort4*)&ks_hi[r][c] = hi;
            *(ushort4*)&ks_lo[r][c] = lo;
        }
        for (int tsk = tid; tsk < 512; tsk += 256) {
            int rp = tsk >> 4;
            int c  = (tsk & 15) << 2;
            float4 a0 = *(const float4*)(vg + (size_t)(2*rp)*D_ + c);
            float4 a1 = *(const float4*)(vg + (size_t)(2*rp+1)*D_ + c);
            #pragma unroll
            for (int j = 0; j < 4; ++j) {
                float x0 = (j==0)?a0.x:(j==1)?a0.y:(j==2)?a0.z:a0.w;
                float x1 = (j==0)?a1.x:(j==1)?a1.y:(j==2)?a1.z:a1.w;
                unsigned short h0 = f2bf(x0), h1b = f2bf(x1);
                *(unsigned*)&vt_hi[c+j][2*rp] = (unsigned)h0 | ((unsigned)h1b << 16);
                unsigned short lo0 = f2bf(x0 - bf2f(h0)), lo1 = f2bf(x1 - bf2f(h1b));
                *(unsigned*)&vt_lo[c+j][2*rp] = (unsigned)lo0 | ((unsigned)lo1 << 16);
            }
        }
        __syncthreads();
        f32x4 sacc[4];
        #pragma unroll
        for (int t = 0; t < 4; ++t) sacc[t] = (f32x4){0.f, 0.f, 0.f, 0.f};
        #pragma unroll
        for (int t = 0; t < 4; ++t) {
            #pragma unroll
            for (int kc = 0; kc < 2; ++kc) {
                bf16x8 khi2 = *(const bf16x8*)&ks_hi[t*16 + l16][kc*32 + quad*8];
                bf16x8 klo2 = *(const bf16x8*)&ks_lo[t*16 + l16][kc*32 + quad*8];
                sacc[t] = __builtin_amdgcn_mfma_f32_16x16x32_bf16(qhi2[kc], khi2, sacc[t], 0, 0, 0);
                sacc[t] = __builtin_amdgcn_mfma_f32_16x16x32_bf16(qhi2[kc], klo2, sacc[t], 0, 0, 0);
                sacc[t] = __builtin_amdgcn_mfma_f32_16x16x32_bf16(qlo2[kc], khi2, sacc[t], 0, 0, 0);
            }
        }
        #pragma unroll
        for (int t = 0; t < 4; ++t) sacc[t] *= 0.125f;
        float rowmax[4];
        #pragma unroll
        for (int r = 0; r < 4; ++r)
            rowmax[r] = fmaxf(fmaxf(sacc[0][r], sacc[1][r]), fmaxf(sacc[2][r], sacc[3][r]));
        #pragma unroll
        for (int off = 1; off < 16; off <<= 1)
            #pragma unroll
            for (int r = 0; r < 4; ++r)
                rowmax[r] = fmaxf(rowmax[r], __shfl_xor(rowmax[r], off));
        float al[4], rs[4];
        #pragma unroll
        for (int r = 0; r < 4; ++r) {
            float mnew = fmaxf(m_i[r], rowmax[r]);
            al[r] = __expf(m_i[r] - mnew);
            m_i[r] = mnew;
            float acc = 0.f;
            #pragma unroll
            for (int t = 0; t < 4; ++t) {
                float p = __expf(sacc[t][r] - mnew);
                unsigned short pb = f2bf(p);
                ps[wave][quad*4 + r][t*16 + l16] = pb;
                acc += bf2f(pb);
            }
            rs[r] = acc;
        }
        #pragma unroll
        for (int off = 1; off < 16; off <<= 1)
            #pragma unroll
            for (int r = 0; r < 4; ++r)
                rs[r] += __shfl_xor(rs[r], off);
        #pragma unroll
        for (int r = 0; r < 4; ++r) l_i[r] = l_i[r] * al[r] + rs[r];
        #pragma unroll
        for (int t = 0; t < 4; ++t)
            #pragma unroll
            for (int r = 0; r < 4; ++r) oacc[t][r] *= al[r];
        bf16x8 pf[2];
        #pragma unroll
        for (int kc = 0; kc < 2; ++kc)
            pf[kc] = *(const bf16x8*)&ps[wave][l16][kc*32 + quad*8];
        #pragma unroll
        for (int t = 0; t < 4; ++t) {
            #pragma unroll
            for (int kc = 0; kc < 2; ++kc) {
                bf16x8 vhif = *(const bf16x8*)&vt_hi[t*16 + l16][kc*32 + quad*8];
                bf16x8 vlof = *(const bf16x8*)&vt_lo[t*16 + l16][kc*32 + quad*8];
                oacc[t] = __builtin_amdgcn_mfma_f32_16x16x32_bf16(pf[kc], vhif, oacc[t], 0, 0, 0);
                oacc[t] = __builtin_amdgcn_mfma_f32_16x16x32_bf16(pf[kc], vlof, oacc[t], 0, 0, 0);
            }
        }
        __syncthreads();
    }
    float* og = out + ((size_t)h*L_ + (size_t)qb*64)*D_ + (size_t)(wave*16 + quad*4)*D_;
    #pragma unroll
    for (int r = 0; r < 4; ++r) {
        float inv = 1.f / l_i[r];
        #pragma unroll
        for (int t = 0; t < 4; ++t)
            og[(size_t)r*D_ + t*16 + l16] = oacc[t][r] * inv;
    }
}

extern "C" void kernel_launch(void* const* d_in, const int* in_sizes, int n_in,
                              void* d_out, int out_size, void* d_ws, size_t ws_size,
                              hipStream_t stream) {
    const float* q = (const float*)d_in[0];
    const float* k = (const float*)d_in[1];
    const float* v = (const float*)d_in[2];
    const int* siq = (const int*)d_in[3];
    const int* sik = (const int*)d_in[4];
    float* out = (float*)d_out;

    char* ws = (char*)d_ws;
    unsigned long long* mask = (unsigned long long*)ws;          // 4 KB
    const size_t TEN = (size_t)H_*L_*D_;                         // 2,097,152 elems
    const size_t SKN = (size_t)H_*1024*64;                       //   524,288 elems
    unsigned short* qhi = (unsigned short*)(ws + 4096);
    unsigned short* qlo = qhi + TEN;
    unsigned short* khi = qlo + TEN;
    unsigned short* vth = khi + TEN;
    unsigned short* skh = vth + TEN;
    unsigned short* skl = skh + SKN;
    const size_t need = 4096 + (4*TEN + 2*SKN)*sizeof(unsigned short);  // ~18.9 MB

    if (ws_size >= need) {
        prep_kernel<<<dim3(H_*NB_), dim3(256), 0, stream>>>(q, k, v, sik, qhi, qlo, khi, vth, skh, skl);
        mask_mfma<<<dim3(H_*NB_), dim3(256), 0, stream>>>(qhi, qlo, skh, skl, siq, mask);
        attn_fast<<<dim3(H_*NB_), dim3(256), 0, stream>>>(qhi, qlo, khi, vth, mask, out);
    } else {
        mask_kernel4<<<dim3(H_*NB_), dim3(256), 0, stream>>>(q, k, siq, sik, mask);
        attn_v3<<<dim3(H_*NB_), dim3(256), 0, stream>>>(q, k, v, mask, out);
    }
}

// Round 10
// 147.099 us; speedup vs baseline: 1.7702x; 1.0061x over previous
//
#include <hip/hip_runtime.h>
#include <hip/hip_bf16.h>

// B=1, H=8, L=4096, D=64; 64x64 blocks; 16 samples/block. Inputs f32, output f32.
#define H_ 8
#define L_ 4096
#define D_ 64
#define NB_ 64

typedef __attribute__((ext_vector_type(8))) short bf16x8;
typedef __attribute__((ext_vector_type(4))) float f32x4;

__device__ __forceinline__ unsigned short f2bf(float x) {   // RNE f32->bf16
    unsigned u = __float_as_uint(x);
    u += 0x7fff + ((u >> 16) & 1);
    return (unsigned short)(u >> 16);
}
__device__ __forceinline__ float bf2f(unsigned short s) {
    return __uint_as_float(((unsigned)s) << 16);
}
// async 16B global -> LDS DMA (no VGPR round-trip, no wave-issued ds_write)
__device__ __forceinline__ void gload_lds16(const unsigned short* g, unsigned short* l) {
    __builtin_amdgcn_global_load_lds(
        (const __attribute__((address_space(1))) unsigned int*)(const void*)g,
        (__attribute__((address_space(3))) unsigned int*)(void*)l,
        16, 0, 0);
}

// ---------------------------------------------------------------------------
// Preprocess (unchanged from round 9).
// ---------------------------------------------------------------------------
__global__ __launch_bounds__(256) void prep_kernel(
    const float* __restrict__ q, const float* __restrict__ k, const float* __restrict__ v,
    const int* __restrict__ sidxk,
    unsigned short* __restrict__ qhi, unsigned short* __restrict__ qlo,
    unsigned short* __restrict__ khi,
    unsigned short* __restrict__ vth,
    unsigned short* __restrict__ skh, unsigned short* __restrict__ skl)
{
    const int h  = blockIdx.x >> 6;
    const int tb = blockIdx.x & 63;
    const int tid = threadIdx.x;
    __shared__ float vst[64][68];

    const size_t te = ((size_t)(h*64 + tb)) << 12;   // tile base (elements)
    const float4* qg = (const float4*)(q + te);
    for (int i4 = tid; i4 < 1024; i4 += 256) {
        float4 t = qg[i4];
        ushort4 hi, lo;
        hi.x = f2bf(t.x); lo.x = f2bf(t.x - bf2f(hi.x));
        hi.y = f2bf(t.y); lo.y = f2bf(t.y - bf2f(hi.y));
        hi.z = f2bf(t.z); lo.z = f2bf(t.z - bf2f(hi.z));
        hi.w = f2bf(t.w); lo.w = f2bf(t.w - bf2f(hi.w));
        *(ushort4*)(qhi + te + i4*4) = hi;
        *(ushort4*)(qlo + te + i4*4) = lo;
    }
    const float4* kg = (const float4*)(k + te);
    for (int i4 = tid; i4 < 1024; i4 += 256) {
        float4 t = kg[i4];
        int r = i4 >> 4, c4 = i4 & 15;
        int sch = (c4 >> 1) ^ ((r >> 2) & 7);   // matches attn's permuted-key S tiles
        ushort4 hi;
        hi.x = f2bf(t.x); hi.y = f2bf(t.y); hi.z = f2bf(t.z); hi.w = f2bf(t.w);
        *(ushort4*)(khi + te + r*64 + sch*8 + (c4 & 1)*4) = hi;
    }
    // sampled-K rows for the MFMA mask
    {
        int t = tid >> 4, d4 = tid & 15;
        int srow = tb*64 + sidxk[h*16 + t];
        float4 x = *(const float4*)(k + ((size_t)h*L_ + srow)*D_ + d4*4);
        ushort4 hi, lo;
        hi.x = f2bf(x.x); lo.x = f2bf(x.x - bf2f(hi.x));
        hi.y = f2bf(x.y); lo.y = f2bf(x.y - bf2f(hi.y));
        hi.z = f2bf(x.z); lo.z = f2bf(x.z - bf2f(hi.z));
        hi.w = f2bf(x.w); lo.w = f2bf(x.w - bf2f(hi.w));
        int sch = (d4 >> 1) ^ (t & 7);
        size_t dst = ((size_t)h*1024 + tb*16 + t)*64 + sch*8 + (d4 & 1)*4;
        *(ushort4*)(skh + dst) = hi;
        *(ushort4*)(skl + dst) = lo;
    }
    const float4* vg = (const float4*)(v + te);
    for (int i4 = tid; i4 < 1024; i4 += 256) {
        float4 t = vg[i4];
        *(float4*)&vst[i4 >> 4][(i4 & 15)*4] = t;
    }
    __syncthreads();
    for (int u = tid; u < 512; u += 256) {
        int d = u >> 3, kc8 = u & 7;
        int sch = kc8 ^ (d & 7);
        ushort4 h0, h1;
        h0.x = f2bf(vst[kc8*8+0][d]); h0.y = f2bf(vst[kc8*8+1][d]);
        h0.z = f2bf(vst[kc8*8+2][d]); h0.w = f2bf(vst[kc8*8+3][d]);
        h1.x = f2bf(vst[kc8*8+4][d]); h1.y = f2bf(vst[kc8*8+5][d]);
        h1.z = f2bf(vst[kc8*8+6][d]); h1.w = f2bf(vst[kc8*8+7][d]);
        *(ushort4*)(vth + te + d*64 + sch*8 + 0) = h0;
        *(ushort4*)(vth + te + d*64 + sch*8 + 4) = h1;
    }
}

// ---------------------------------------------------------------------------
// Kernel A (v5.2): MFMA block mask.
// ROUND 10: XCD-affinity block remap h=bid&7 (was bid>>6). Round-robin
// blockIdx->XCD dispatch then keeps all blocks of a head on ONE XCD, whose
// L2 holds that head's 0.5 MB skh/skl working set. Pure index remap —
// bit-identical output.
// ---------------------------------------------------------------------------
__global__ __launch_bounds__(256, 4) void mask_mfma(
    const unsigned short* __restrict__ qhi, const unsigned short* __restrict__ qlo,
    const unsigned short* __restrict__ skh, const unsigned short* __restrict__ skl,
    const int* __restrict__ sidxq,
    unsigned long long* __restrict__ maskbits)
{
    const int h    = blockIdx.x & 7;    // XCD-affinity remap
    const int qb   = blockIdx.x >> 3;
    const int tid  = threadIdx.x;
    const int wave = tid >> 6;
    const int lane = tid & 63;
    const int l16  = lane & 15;
    const int quad = lane >> 4;

    __shared__ __align__(16) unsigned short ch[8192];
    __shared__ __align__(16) unsigned short cl[8192];
    __shared__ float E[16][64];
    __shared__ float Z[16];
    __shared__ float pooled[64];

    for (int e = tid; e < 16*64; e += 256) (&E[0][0])[e] = 0.f;

    const int iqr = sidxq[h*16 + l16];
    const size_t qo = (((size_t)(h*64 + qb)) << 12) + (size_t)iqr*64;
    bf16x8 qh[2], ql[2];
    qh[0] = *(const bf16x8*)(qhi + qo + quad*8);
    qh[1] = *(const bf16x8*)(qhi + qo + 32 + quad*8);
    ql[0] = *(const bf16x8*)(qlo + qo + quad*8);
    ql[1] = *(const bf16x8*)(qlo + qo + 32 + quad*8);
    __syncthreads();

    for (int cc = 0; cc < 8; ++cc) {
        const bf16x8* gh = (const bf16x8*)(skh + ((size_t)h*1024 + cc*128)*64);
        const bf16x8* gl = (const bf16x8*)(skl + ((size_t)h*1024 + cc*128)*64);
        for (int i = tid; i < 1024; i += 256) {
            ((bf16x8*)ch)[i] = gh[i];
            ((bf16x8*)cl)[i] = gl[i];
        }
        __syncthreads();

        #pragma unroll
        for (int tt = 0; tt < 2; ++tt) {
            const int kb = cc*8 + wave*2 + tt;
            const int nb = (wave*2 + tt)*16;
            f32x4 sacc = (f32x4){0.f, 0.f, 0.f, 0.f};
            #pragma unroll
            for (int kc = 0; kc < 2; ++kc) {
                const int off = (nb + l16)*64 + (((kc*4 + quad) ^ (l16 & 7))*8);
                bf16x8 kh = *(const bf16x8*)&ch[off];
                bf16x8 kl = *(const bf16x8*)&cl[off];
                sacc = __builtin_amdgcn_mfma_f32_16x16x32_bf16(qh[kc], kh, sacc, 0, 0, 0);
                sacc = __builtin_amdgcn_mfma_f32_16x16x32_bf16(qh[kc], kl, sacc, 0, 0, 0);
                sacc = __builtin_amdgcn_mfma_f32_16x16x32_bf16(ql[kc], kh, sacc, 0, 0, 0);
                sacc = __builtin_amdgcn_mfma_f32_16x16x32_bf16(ql[kc], kl, sacc, 0, 0, 0);
            }
            #pragma unroll
            for (int r = 0; r < 4; ++r) {
                float p = __expf(sacc[r] * 0.125f);
                p += __shfl_xor(p, 1);
                p += __shfl_xor(p, 2);
                p += __shfl_xor(p, 4);
                p += __shfl_xor(p, 8);
                if (l16 == 0) E[quad*4 + r][kb] = p;
            }
        }
        __syncthreads();
    }

    if (tid < 16) {
        float s = 0.f;
        #pragma unroll
        for (int kb = 0; kb < 64; ++kb) s += E[tid][kb];
        Z[tid] = s;
    }
    __syncthreads();
    if (tid < 64) {
        float s = 0.f;
        #pragma unroll
        for (int t = 0; t < 16; ++t) s += E[t][tid] / Z[t];
        pooled[tid] = s;
    }
    __syncthreads();
    if (tid < 64) {
        float pi = pooled[tid];
        float tot = 0.f, bef = 0.f;
        for (int j2 = 0; j2 < 64; ++j2) {
            float pj = pooled[j2];
            tot += pj;
            if (pj > pi || (pj == pi && j2 < tid)) bef += pj;
        }
        bool att = (bef / tot) < 0.5f;
        unsigned long long bits = __ballot(att);
        if (tid == 0) maskbits[h*64 + qb] = bits;
    }
}

// ---------------------------------------------------------------------------
// Kernel B (v7.1): block-sparse flash attention, fixed-M softmax.
// ROUND 10: XCD-affinity block remap h=bid&7. Round-8 counters showed
// FETCH_SIZE=36.7MB vs ~16MB unique ws: with h=bid>>6, each head's blocks
// scatter over all 8 XCDs, so every 4MB L2 tries to cache all 8 heads'
// K/V (8MB) -> thrash -> the per-iter global_load_lds runs at HBM/L3
// latency and the barrier's vmcnt(0) drain eats it. With same-h blocks on
// one XCD the head's 1MB khi+vth is L2-resident. Bit-identical output.
// ---------------------------------------------------------------------------
__global__ __launch_bounds__(256, 2) void attn_fast(
    const unsigned short* __restrict__ qhi, const unsigned short* __restrict__ qlo,
    const unsigned short* __restrict__ khi,
    const unsigned short* __restrict__ vth,
    const unsigned long long* __restrict__ maskbits,
    float* __restrict__ out)
{
    const int h    = blockIdx.x & 7;    // XCD-affinity remap
    const int qb   = blockIdx.x >> 3;
    const int tid  = threadIdx.x;
    const int wave = tid >> 6;
    const int lane = tid & 63;
    const int l16  = lane & 15;
    const int quad = lane >> 4;

    __shared__ __align__(16) unsigned short bufK[2][4096];
    __shared__ __align__(16) unsigned short bufVh[2][4096];
    __shared__ __align__(16) unsigned short ps[4][16][88];

    const size_t qoff = (((size_t)(h*64 + qb)) << 12) + (size_t)(wave*16 + l16)*64;
    bf16x8 qfh[2], qfl[2];
    qfh[0] = *(const bf16x8*)(qhi + qoff + quad*8);
    qfh[1] = *(const bf16x8*)(qhi + qoff + 32 + quad*8);
    qfl[0] = *(const bf16x8*)(qlo + qoff + quad*8);
    qfl[1] = *(const bf16x8*)(qlo + qoff + 32 + quad*8);

    const unsigned long long bm = maskbits[(h << 6) + qb];

    float lpart[4];
    f32x4 oacc[4];
    #pragma unroll
    for (int r = 0; r < 4; ++r) lpart[r] = 0.f;
    #pragma unroll
    for (int t = 0; t < 4; ++t) oacc[t] = (f32x4){0.f, 0.f, 0.f, 0.f};

    auto dma_stage = [&](int kb, int b) {
        const size_t tb = ((size_t)(h*64 + kb)) << 12;
        gload_lds16(khi + tb + tid*8,         &bufK [b][tid*8]);
        gload_lds16(khi + tb + (tid+256)*8,   &bufK [b][(tid+256)*8]);
        gload_lds16(vth + tb + tid*8,         &bufVh[b][tid*8]);
        gload_lds16(vth + tb + (tid+256)*8,   &bufVh[b][(tid+256)*8]);
    };

    auto compute = [&](int b) {
        f32x4 sacc[4];
        #pragma unroll
        for (int t = 0; t < 4; ++t) sacc[t] = (f32x4){0.f, 0.f, 0.f, 0.f};
        // S: tile t covers keys l16*4+t (permuted); swizzle matches prep's
        // ^((key>>2)&7) since (l16*4+t)>>2 == l16.
        #pragma unroll
        for (int t = 0; t < 4; ++t) {
            #pragma unroll
            for (int kc = 0; kc < 2; ++kc) {
                bf16x8 kf = *(const bf16x8*)&bufK[b][(l16*4 + t)*64 + (((kc*4 + quad) ^ (l16 & 7))*8)];
                sacc[t] = __builtin_amdgcn_mfma_f32_16x16x32_bf16(qfh[kc], kf, sacc[t], 0, 0, 0);
                sacc[t] = __builtin_amdgcn_mfma_f32_16x16x32_bf16(qfl[kc], kf, sacc[t], 0, 0, 0);
            }
        }
        // p = exp(s*0.125 - 16); keys l16*4+0..3 -> one b64 write per row
        #pragma unroll
        for (int r = 0; r < 4; ++r) {
            float p0 = __expf(fmaf(sacc[0][r], 0.125f, -16.0f));
            float p1 = __expf(fmaf(sacc[1][r], 0.125f, -16.0f));
            float p2 = __expf(fmaf(sacc[2][r], 0.125f, -16.0f));
            float p3 = __expf(fmaf(sacc[3][r], 0.125f, -16.0f));
            __hip_bfloat162 a01 = __float22bfloat162_rn(make_float2(p0, p1));
            __hip_bfloat162 a23 = __float22bfloat162_rn(make_float2(p2, p3));
            unsigned u01 = *(unsigned*)&a01;
            unsigned u23 = *(unsigned*)&a23;
            uint2 w; w.x = u01; w.y = u23;
            *(uint2*)&ps[wave][quad*4 + r][l16*4] = w;
            lpart[r] += (bf2f((unsigned short)(u01 & 0xffffu)) + bf2f((unsigned short)(u01 >> 16)))
                      + (bf2f((unsigned short)(u23 & 0xffffu)) + bf2f((unsigned short)(u23 >> 16)));
        }
        // PV: ps indexed by physical key -> contiguous A-frag reads
        bf16x8 pf[2];
        #pragma unroll
        for (int kc = 0; kc < 2; ++kc)
            pf[kc] = *(const bf16x8*)&ps[wave][l16][kc*32 + quad*8];
        #pragma unroll
        for (int t = 0; t < 4; ++t) {
            #pragma unroll
            for (int kc = 0; kc < 2; ++kc) {
                bf16x8 vh = *(const bf16x8*)&bufVh[b][(t*16 + l16)*64 + (((kc*4 + quad) ^ (l16 & 7))*8)];
                oacc[t] = __builtin_amdgcn_mfma_f32_16x16x32_bf16(pf[kc], vh, oacc[t], 0, 0, 0);
            }
        }
    };

    unsigned long long rem = bm;
    int cur = 0;
    {
        int kb0 = (int)__builtin_ctzll(rem); rem &= rem - 1;
        dma_stage(kb0, 0);
    }
    for (;;) {
        __syncthreads();
        int nxt = -1;
        if (rem) { nxt = (int)__builtin_ctzll(rem); rem &= rem - 1; dma_stage(nxt, cur ^ 1); }
        compute(cur);
        if (nxt < 0) break;
        cur ^= 1;
    }

    #pragma unroll
    for (int off = 1; off < 16; off <<= 1)
        #pragma unroll
        for (int r = 0; r < 4; ++r)
            lpart[r] += __shfl_xor(lpart[r], off);

    float* og = out + ((size_t)h*L_ + (size_t)qb*64)*D_ + (size_t)(wave*16 + quad*4)*D_;
    #pragma unroll
    for (int r = 0; r < 4; ++r) {
        float inv = 1.f / lpart[r];
        #pragma unroll
        for (int t = 0; t < 4; ++t)
            og[(size_t)r*D_ + t*16 + l16] = oacc[t][r] * inv;
    }
}

// ---------------------------------------------------------------------------
// Fallback path (round-6, proven): mask_kernel4 + attn_v3, only if ws small.
// ---------------------------------------------------------------------------
__global__ __launch_bounds__(256, 4) void mask_kernel4(
    const float* __restrict__ q, const float* __restrict__ k,
    const int* __restrict__ sidxq, const int* __restrict__ sidxk,
    unsigned long long* __restrict__ maskbits)
{
    const int h   = blockIdx.x >> 6;
    const int qb  = blockIdx.x & 63;
    const int tid = threadIdx.x;
    const int rg  = tid >> 5;
    const int cg  = tid & 31;

    __shared__ float sq[16][68];
    __shared__ float skc[128][68];
    __shared__ float E[16][64];
    __shared__ float Z[16];
    __shared__ float pooled[64];
    __shared__ int iq[16], ik[16];

    if (tid < 16) { iq[tid] = sidxq[h*16 + tid]; ik[tid] = sidxk[h*16 + tid]; }
    for (int e = tid; e < 16*64; e += 256) (&E[0][0])[e] = 0.f;
    __syncthreads();
    {
        int j = tid >> 4, d4 = tid & 15;
        int grow = h*L_ + qb*64 + iq[j];
        *(float4*)&sq[j][d4*4] = *(const float4*)(q + (size_t)grow*D_ + d4*4);
    }
    for (int cc = 0; cc < 8; ++cc) {
        for (int i = tid; i < 2048; i += 256) {
            int col = i >> 4, d4 = i & 15;
            int colg = cc*128 + col;
            int grow = h*L_ + (colg >> 4)*64 + ik[colg & 15];
            *(float4*)&skc[col][d4*4] = *(const float4*)(k + (size_t)grow*D_ + d4*4);
        }
        __syncthreads();
        float acc[2][4] = {{0.f,0.f,0.f,0.f},{0.f,0.f,0.f,0.f}};
        #pragma unroll 4
        for (int d4 = 0; d4 < 16; ++d4) {
            float4 qv0 = *(const float4*)&sq[rg*2 + 0][d4*4];
            float4 qv1 = *(const float4*)&sq[rg*2 + 1][d4*4];
            #pragma unroll
            for (int j = 0; j < 4; ++j) {
                float4 kv = *(const float4*)&skc[cg + 32*j][d4*4];
                acc[0][j] += qv0.x*kv.x + qv0.y*kv.y + qv0.z*kv.z + qv0.w*kv.w;
                acc[1][j] += qv1.x*kv.x + qv1.y*kv.y + qv1.z*kv.z + qv1.w*kv.w;
            }
        }
        #pragma unroll
        for (int j = 0; j < 4; ++j) {
            int kb = cc*8 + (cg >> 4) + 2*j;
            #pragma unroll
            for (int i = 0; i < 2; ++i) {
                float p = __expf(acc[i][j] * 0.125f);
                p += __shfl_xor(p, 1);
                p += __shfl_xor(p, 2);
                p += __shfl_xor(p, 4);
                p += __shfl_xor(p, 8);
                if ((cg & 15) == 0) E[rg*2 + i][kb] += p;
            }
        }
        __syncthreads();
    }
    if (tid < 16) {
        float s = 0.f;
        #pragma unroll
        for (int kb = 0; kb < 64; ++kb) s += E[tid][kb];
        Z[tid] = s;
    }
    __syncthreads();
    if (tid < 64) {
        float s = 0.f;
        #pragma unroll
        for (int t = 0; t < 16; ++t) s += E[t][tid] / Z[t];
        pooled[tid] = s;
    }
    __syncthreads();
    if (tid < 64) {
        float pi = pooled[tid];
        float tot = 0.f, bef = 0.f;
        for (int j2 = 0; j2 < 64; ++j2) {
            float pj = pooled[j2];
            tot += pj;
            if (pj > pi || (pj == pi && j2 < tid)) bef += pj;
        }
        bool att = (bef / tot) < 0.5f;
        unsigned long long bits = __ballot(att);
        if (tid == 0) maskbits[h*64 + qb] = bits;
    }
}

__global__ __launch_bounds__(256, 3) void attn_v3(
    const float* __restrict__ q, const float* __restrict__ k, const float* __restrict__ v,
    const unsigned long long* __restrict__ maskbits, float* __restrict__ out)
{
    const int h = blockIdx.x >> 6, qb = blockIdx.x & 63;
    const int tid = threadIdx.x, wave = tid >> 6, lane = tid & 63;
    const int l16 = lane & 15, quad = lane >> 4;
    __shared__ __align__(16) unsigned short ks_hi[64][72];
    __shared__ __align__(16) unsigned short ks_lo[64][72];
    __shared__ __align__(16) unsigned short vt_hi[64][72];
    __shared__ __align__(16) unsigned short vt_lo[64][72];
    __shared__ __align__(16) unsigned short ps[4][16][72];

    const float4* qg = (const float4*)(q + ((size_t)h*L_ + (size_t)qb*64)*D_);
    for (int i4 = tid; i4 < 1024; i4 += 256) {
        float4 t = qg[i4];
        int r = i4 >> 4, c = (i4 & 15) << 2;
        ushort4 hi, lo;
        hi.x = f2bf(t.x); lo.x = f2bf(t.x - bf2f(hi.x));
        hi.y = f2bf(t.y); lo.y = f2bf(t.y - bf2f(hi.y));
        hi.z = f2bf(t.z); lo.z = f2bf(t.z - bf2f(hi.z));
        hi.w = f2bf(t.w); lo.w = f2bf(t.w - bf2f(hi.w));
        *(ushort4*)&ks_hi[r][c] = hi;
        *(ushort4*)&ks_lo[r][c] = lo;
    }
    const unsigned long long bm = maskbits[(h << 6) + qb];
    __syncthreads();
    bf16x8 qhi2[2], qlo2[2];
    #pragma unroll
    for (int kc = 0; kc < 2; ++kc) {
        qhi2[kc] = *(const bf16x8*)&ks_hi[wave*16 + l16][kc*32 + quad*8];
        qlo2[kc] = *(const bf16x8*)&ks_lo[wave*16 + l16][kc*32 + quad*8];
    }
    __syncthreads();
    float m_i[4], l_i[4];
    f32x4 oacc[4];
    #pragma unroll
    for (int r = 0; r < 4; ++r) { m_i[r] = -1e30f; l_i[r] = 0.f; }
    #pragma unroll
    for (int t = 0; t < 4; ++t) oacc[t] = (f32x4){0.f, 0.f, 0.f, 0.f};
    for (int kb = 0; kb < 64; ++kb) {
        if (!((bm >> kb) & 1ull)) continue;
        const float4* kg = (const float4*)(k + ((size_t)h*L_ + (size_t)kb*64)*D_);
        const float*  vg = v + ((size_t)h*L_ + (size_t)kb*64)*D_;
        for (int i4 = tid; i4 < 1024; i4 += 256) {
            float4 t = kg[i4];
            int r = i4 >> 4, c = (i4 & 15) << 2;
            ushort4 hi, lo;
            hi.x = f2bf(t.x); lo.x = f2bf(t.x - bf2f(hi.x));
            hi.y = f2bf(t.y); lo.y = f2bf(t.y - bf2f(hi.y));
            hi.z = f2bf(t.z); lo.z = f2bf(t.z - bf2f(hi.z));
            hi.w = f2bf(t.w); lo.w = f2bf(t.w - bf2f(hi.w));
            *(ushort4*)&ks_hi[r][c] = hi;
            *(ushort4*)&ks_lo[r][c] = lo;
        }
        for (int tsk = tid; tsk < 512; tsk += 256) {
            int rp = tsk >> 4;
            int c  = (tsk & 15) << 2;
            float4 a0 = *(const float4*)(vg + (size_t)(2*rp)*D_ + c);
            float4 a1 = *(const float4*)(vg + (size_t)(2*rp+1)*D_ + c);
            #pragma unroll
            for (int j = 0; j < 4; ++j) {
                float x0 = (j==0)?a0.x:(j==1)?a0.y:(j==2)?a0.z:a0.w;
                float x1 = (j==0)?a1.x:(j==1)?a1.y:(j==2)?a1.z:a1.w;
                unsigned short h0 = f2bf(x0), h1b = f2bf(x1);
                *(unsigned*)&vt_hi[c+j][2*rp] = (unsigned)h0 | ((unsigned)h1b << 16);
                unsigned short lo0 = f2bf(x0 - bf2f(h0)), lo1 = f2bf(x1 - bf2f(h1b));
                *(unsigned*)&vt_lo[c+j][2*rp] = (unsigned)lo0 | ((unsigned)lo1 << 16);
            }
        }
        __syncthreads();
        f32x4 sacc[4];
        #pragma unroll
        for (int t = 0; t < 4; ++t) sacc[t] = (f32x4){0.f, 0.f, 0.f, 0.f};
        #pragma unroll
        for (int t = 0; t < 4; ++t) {
            #pragma unroll
            for (int kc = 0; kc < 2; ++kc) {
                bf16x8 khi2 = *(const bf16x8*)&ks_hi[t*16 + l16][kc*32 + quad*8];
                bf16x8 klo2 = *(const bf16x8*)&ks_lo[t*16 + l16][kc*32 + quad*8];
                sacc[t] = __builtin_amdgcn_mfma_f32_16x16x32_bf16(qhi2[kc], khi2, sacc[t], 0, 0, 0);
                sacc[t] = __builtin_amdgcn_mfma_f32_16x16x32_bf16(qhi2[kc], klo2, sacc[t], 0, 0, 0);
                sacc[t] = __builtin_amdgcn_mfma_f32_16x16x32_bf16(qlo2[kc], khi2, sacc[t], 0, 0, 0);
            }
        }
        #pragma unroll
        for (int t = 0; t < 4; ++t) sacc[t] *= 0.125f;
        float rowmax[4];
        #pragma unroll
        for (int r = 0; r < 4; ++r)
            rowmax[r] = fmaxf(fmaxf(sacc[0][r], sacc[1][r]), fmaxf(sacc[2][r], sacc[3][r]));
        #pragma unroll
        for (int off = 1; off < 16; off <<= 1)
            #pragma unroll
            for (int r = 0; r < 4; ++r)
                rowmax[r] = fmaxf(rowmax[r], __shfl_xor(rowmax[r], off));
        float al[4], rs[4];
        #pragma unroll
        for (int r = 0; r < 4; ++r) {
            float mnew = fmaxf(m_i[r], rowmax[r]);
            al[r] = __expf(m_i[r] - mnew);
            m_i[r] = mnew;
            float acc = 0.f;
            #pragma unroll
            for (int t = 0; t < 4; ++t) {
                float p = __expf(sacc[t][r] - mnew);
                unsigned short pb = f2bf(p);
                ps[wave][quad*4 + r][t*16 + l16] = pb;
                acc += bf2f(pb);
            }
            rs[r] = acc;
        }
        #pragma unroll
        for (int off = 1; off < 16; off <<= 1)
            #pragma unroll
            for (int r = 0; r < 4; ++r)
                rs[r] += __shfl_xor(rs[r], off);
        #pragma unroll
        for (int r = 0; r < 4; ++r) l_i[r] = l_i[r] * al[r] + rs[r];
        #pragma unroll
        for (int t = 0; t < 4; ++t)
            #pragma unroll
            for (int r = 0; r < 4; ++r) oacc[t][r] *= al[r];
        bf16x8 pf[2];
        #pragma unroll
        for (int kc = 0; kc < 2; ++kc)
            pf[kc] = *(const bf16x8*)&ps[wave][l16][kc*32 + quad*8];
        #pragma unroll
        for (int t = 0; t < 4; ++t) {
            #pragma unroll
            for (int kc = 0; kc < 2; ++kc) {
                bf16x8 vhif = *(const bf16x8*)&vt_hi[t*16 + l16][kc*32 + quad*8];
                bf16x8 vlof = *(const bf16x8*)&vt_lo[t*16 + l16][kc*32 + quad*8];
                oacc[t] = __builtin_amdgcn_mfma_f32_16x16x32_bf16(pf[kc], vhif, oacc[t], 0, 0, 0);
                oacc[t] = __builtin_amdgcn_mfma_f32_16x16x32_bf16(pf[kc], vlof, oacc[t], 0, 0, 0);
            }
        }
        __syncthreads();
    }
    float* og = out + ((size_t)h*L_ + (size_t)qb*64)*D_ + (size_t)(wave*16 + quad*4)*D_;
    #pragma unroll
    for (int r = 0; r < 4; ++r) {
        float inv = 1.f / l_i[r];
        #pragma unroll
        for (int t = 0; t < 4; ++t)
            og[(size_t)r*D_ + t*16 + l16] = oacc[t][r] * inv;
    }
}

extern "C" void kernel_launch(void* const* d_in, const int* in_sizes, int n_in,
                              void* d_out, int out_size, void* d_ws, size_t ws_size,
                              hipStream_t stream) {
    const float* q = (const float*)d_in[0];
    const float* k = (const float*)d_in[1];
    const float* v = (const float*)d_in[2];
    const int* siq = (const int*)d_in[3];
    const int* sik = (const int*)d_in[4];
    float* out = (float*)d_out;

    char* ws = (char*)d_ws;
    unsigned long long* mask = (unsigned long long*)ws;          // 4 KB
    const size_t TEN = (size_t)H_*L_*D_;                         // 2,097,152 elems
    const size_t SKN = (size_t)H_*1024*64;                       //   524,288 elems
    unsigned short* qhi = (unsigned short*)(ws + 4096);
    unsigned short* qlo = qhi + TEN;
    unsigned short* khi = qlo + TEN;
    unsigned short* vth = khi + TEN;
    unsigned short* skh = vth + TEN;
    unsigned short* skl = skh + SKN;
    const size_t need = 4096 + (4*TEN + 2*SKN)*sizeof(unsigned short);  // ~18.9 MB

    if (ws_size >= need) {
        prep_kernel<<<dim3(H_*NB_), dim3(256), 0, stream>>>(q, k, v, sik, qhi, qlo, khi, vth, skh, skl);
        mask_mfma<<<dim3(H_*NB_), dim3(256), 0, stream>>>(qhi, qlo, skh, skl, siq, mask);
        attn_fast<<<dim3(H_*NB_), dim3(256), 0, stream>>>(qhi, qlo, khi, vth, mask, out);
    } else {
        mask_kernel4<<<dim3(H_*NB_), dim3(256), 0, stream>>>(q, k, siq, sik, mask);
        attn_v3<<<dim3(H_*NB_), dim3(256), 0, stream>>>(q, k, v, mask, out);
    }
}